// Round 3
// baseline (535.894 us; speedup 1.0000x reference)
//
#include <hip/hip_runtime.h>
#include <cstdint>
#include <cstddef>

typedef __bf16 bf16x8 __attribute__((ext_vector_type(8)));
typedef __bf16 bf16x4 __attribute__((ext_vector_type(4)));
typedef float f32x4 __attribute__((ext_vector_type(4)));
static_assert(sizeof(bf16x8) == 16, "bf16x8 must be 16B");
static_assert(sizeof(bf16x4) == 8, "bf16x4 must be 8B");
static_assert(sizeof(f32x4) == 16, "f32x4 must be 16B");

#define MFMA16(a, b, c) __builtin_amdgcn_mfma_f32_16x16x32_bf16((a), (b), (c), 0, 0, 0)
#define SBAR() __builtin_amdgcn_s_barrier()
#define LGKM0() asm volatile("s_waitcnt lgkmcnt(0)" ::: "memory")
#define VMCNT(n_) asm volatile("s_waitcnt vmcnt(" #n_ ")" ::: "memory")

__device__ __forceinline__ void gload_lds16(const void* g, void* l) {
  __builtin_amdgcn_global_load_lds(
      (const __attribute__((address_space(1))) void*)g,
      (__attribute__((address_space(3))) void*)l, 16, 0, 0);
}

// ---------------------------------------------------------------- conv x -> bf16
__global__ __launch_bounds__(256) void conv_x_kernel(const float* __restrict__ in,
                                                     __bf16* __restrict__ out) {
  size_t i = ((size_t)blockIdx.x * 256 + threadIdx.x) * 4;
  const float4 v = *(const float4*)(in + i);
  bf16x4 pk;
  pk[0] = (__bf16)v.x;
  pk[1] = (__bf16)v.y;
  pk[2] = (__bf16)v.z;
  pk[3] = (__bf16)v.w;
  *(bf16x4*)(out + i) = pk;
}

// ------------------------------------------- transpose fp32 [K][N] -> bf16 [N][K]
__global__ __launch_bounds__(256) void transpose_conv_kernel(const float* __restrict__ in,
                                                             __bf16* __restrict__ out,
                                                             int K, int N) {
  __shared__ float tile[32][33];
  const int n0 = blockIdx.x * 32, k0 = blockIdx.y * 32;
  const int tx = threadIdx.x, ty = threadIdx.y;  // (32, 8)
#pragma unroll
  for (int i = 0; i < 4; ++i)
    tile[ty * 4 + i][tx] = in[(size_t)(k0 + ty * 4 + i) * N + n0 + tx];
  __syncthreads();
#pragma unroll
  for (int i = 0; i < 4; ++i)
    out[(size_t)(n0 + ty * 4 + i) * K + k0 + tx] = (__bf16)tile[tx][ty * 4 + i];
}

// ------------------------------------------------------- rel-pos bias gather (TRANSPOSED)
// biasT[h][j][i] = table[ids[i*256+j]*12 + h]  -> attn reads f32x4 along i
__global__ __launch_bounds__(256) void bias_gather_kernel(const float* __restrict__ table,
                                                          const int* __restrict__ ids,
                                                          float* __restrict__ biasT) {
  const int idx = blockIdx.x * 256 + threadIdx.x;  // h*65536 + j*256 + i
  const int h = idx >> 16, ji = idx & 65535;
  const int j = ji >> 8, i = ji & 255;
  biasT[idx] = table[ids[i * 256 + j] * 12 + h];
}

// ---------------------------------------------------------------- bf16 GEMM (8-phase)
// C[M,N] = A[M,K] * Bt^T. 256x256 tile, BK=64, 8 waves (2M x 4N), per-wave 128x64.
// Double-buffered 128 KiB LDS, 4 phases per K-tile, counted vmcnt (never 0 in loop),
// setprio around MFMA clusters, bijective XCD swizzle (grid % 8 == 0).
// Epilogue: acc -> LDS (slot-XOR swizzled, conflict-free) -> fully coalesced
// 16B-per-lane stores.
// MODE 0: -> packed Q(scaled)/K [b,h,tok,d]; MODE 1: -> fp32 C+bias;
// MODE 2: -> packed V^T [b,h,d,tok]
template <int MODE, int NT>
__global__ __launch_bounds__(512, 2) void gemm8_kernel(const __bf16* __restrict__ A,
                                                       const __bf16* __restrict__ Bt,
                                                       const float* __restrict__ bias,
                                                       void* __restrict__ out0,
                                                       __bf16* __restrict__ kbuf,
                                                       const int M, const int N, const int K) {
  constexpr bool TRANS = (MODE != 2);
  __shared__ __align__(16) __bf16 smem[65536];  // 128 KiB: [2 buf][A|B][256][64]
  const int tid = threadIdx.x;
  const int lane = tid & 63, w = tid >> 6;  // 8 waves
  const int m16 = lane & 15, q4 = lane >> 4;
  const int wm = w & 1, wn = w >> 1;  // 2 x 4 wave grid

  // bijective XCD swizzle: nwg % 8 == 0 for all launches here
  const int nwg = NT * (M >> 8);
  const int chunk = nwg >> 3;
  const int id = blockIdx.x;
  const int wg = (id & 7) * chunk + (id >> 3);
  const int mi = wg / NT, ni = wg - mi * NT;
  const int m0 = mi << 8, n0 = ni << 8;

  // ---- staging addressing: per-lane global src, wave-uniform LDS dst (+lane*16B in HW)
  const int srow = w * 8 + (lane >> 3);               // 0..63
  const int sg = ((lane & 7) ^ (srow & 7)) * 8;       // XOR-swizzled col group (constant)
  const __bf16* ag = A + (size_t)(m0 + srow) * K + sg;
  const __bf16* bg = Bt + (size_t)(n0 + srow) * K + sg;
  const int dstw = w * 512;

  // ---- frag-read offsets (elements); row&7 == m16&7 for all frag rows
  const int g0 = (q4 ^ (m16 & 7)) * 8;
  const int g1 = ((4 + q4) ^ (m16 & 7)) * 8;
  const int abase = (wm * 128 + m16) * 64;
  const int bbase = 16384 + (wn * 64 + m16) * 64;

  const int nt = K >> 6;  // 12 for all launches here (>= 2 required)

#define STAGE(T_, mat_, h_)                                                        \
  do {                                                                             \
    const __bf16* s_ = ((mat_) ? bg : ag) + (size_t)(T_)*64 + (size_t)(h_)*128 * K; \
    __bf16* d_ = &smem[((T_)&1) * 32768 + (mat_)*16384 + (h_)*8192 + dstw];        \
    gload_lds16(s_, d_);                                                           \
    gload_lds16(s_ + (size_t)64 * K, d_ + 4096);                                   \
  } while (0)

#define MM(a_, b_, c_) (TRANS ? MFMA16((b_), (a_), (c_)) : MFMA16((a_), (b_), (c_)))

  // ---- prologue: tile0 fully + A(1)h0; wait tile0 (leave A(1)h0 in flight)
  STAGE(0, 0, 0);
  STAGE(0, 0, 1);
  STAGE(0, 1, 0);
  STAGE(0, 1, 1);
  STAGE(1, 0, 0);
  VMCNT(2);
  SBAR();

  f32x4 acc[8][4] = {};
  for (int T = 0; T < nt; ++T) {
    const int base = (T & 1) * 32768;
    bf16x8 a[4][2], b0[2][2], b1[2][2];

    // -------- P1: quadrant (m-half0, n-half0); reads A m0 (8) + B n0 (4)
#pragma unroll
    for (int fm = 0; fm < 4; ++fm) {
      a[fm][0] = *(const bf16x8*)&smem[base + abase + fm * 1024 + g0];
      a[fm][1] = *(const bf16x8*)&smem[base + abase + fm * 1024 + g1];
    }
#pragma unroll
    for (int fn = 0; fn < 2; ++fn) {
      b0[fn][0] = *(const bf16x8*)&smem[base + bbase + fn * 1024 + g0];
      b0[fn][1] = *(const bf16x8*)&smem[base + bbase + fn * 1024 + g1];
    }
    if (T + 1 < nt) STAGE(T + 1, 0, 1);
    SBAR();
    LGKM0();
    __builtin_amdgcn_s_setprio(1);
#pragma unroll
    for (int kh = 0; kh < 2; ++kh)
#pragma unroll
      for (int fm = 0; fm < 4; ++fm)
#pragma unroll
        for (int fn = 0; fn < 2; ++fn)
          acc[fm][fn] = MM(a[fm][kh], b0[fn][kh], acc[fm][fn]);
    __builtin_amdgcn_s_setprio(0);
    SBAR();

    // -------- P2: quadrant (m0, n1); reads B n1 (4)
#pragma unroll
    for (int fn = 0; fn < 2; ++fn) {
      b1[fn][0] = *(const bf16x8*)&smem[base + bbase + 2048 + fn * 1024 + g0];
      b1[fn][1] = *(const bf16x8*)&smem[base + bbase + 2048 + fn * 1024 + g1];
    }
    if (T + 1 < nt) {
      STAGE(T + 1, 1, 0);
      STAGE(T + 1, 1, 1);
    }
    SBAR();
    LGKM0();
    __builtin_amdgcn_s_setprio(1);
#pragma unroll
    for (int kh = 0; kh < 2; ++kh)
#pragma unroll
      for (int fm = 0; fm < 4; ++fm)
#pragma unroll
        for (int fn = 0; fn < 2; ++fn)
          acc[fm][2 + fn] = MM(a[fm][kh], b1[fn][kh], acc[fm][2 + fn]);
    __builtin_amdgcn_s_setprio(0);
    SBAR();

    // -------- P3: quadrant (m1, n1); reads A m1 (8)
#pragma unroll
    for (int fm = 0; fm < 4; ++fm) {
      a[fm][0] = *(const bf16x8*)&smem[base + abase + 4096 + fm * 1024 + g0];
      a[fm][1] = *(const bf16x8*)&smem[base + abase + 4096 + fm * 1024 + g1];
    }
    SBAR();
    LGKM0();
    __builtin_amdgcn_s_setprio(1);
#pragma unroll
    for (int kh = 0; kh < 2; ++kh)
#pragma unroll
      for (int fm = 0; fm < 4; ++fm)
#pragma unroll
        for (int fn = 0; fn < 2; ++fn)
          acc[4 + fm][2 + fn] = MM(a[fm][kh], b1[fn][kh], acc[4 + fm][2 + fn]);
    __builtin_amdgcn_s_setprio(0);
    SBAR();

    // -------- P4: quadrant (m1, n0); no reads; counted vmcnt once per K-tile
    if (T + 2 < nt) {
      STAGE(T + 2, 0, 0);
      VMCNT(2);
    } else if (T + 1 < nt) {
      VMCNT(0);
    }
    SBAR();
    __builtin_amdgcn_s_setprio(1);
#pragma unroll
    for (int kh = 0; kh < 2; ++kh)
#pragma unroll
      for (int fm = 0; fm < 4; ++fm)
#pragma unroll
        for (int fn = 0; fn < 2; ++fn)
          acc[4 + fm][fn] = MM(a[fm][kh], b0[fn][kh], acc[4 + fm][fn]);
    __builtin_amdgcn_s_setprio(0);
    SBAR();
  }
#undef STAGE
#undef MM

  // ---------------- epilogue: LDS transpose -> coalesced stores
  __syncthreads();  // all loop LDS traffic retired; smem reusable

  if (MODE == 0) {
    // acc (TRANS): value C[n][tok], r -> n, m16 -> tok.
    // LDS tile: [256 tok][256 n bf16] rows of 512 B, 16B-slot s' = s ^ (tok&7).
    const int which = (n0 >= 768);
    const float qscale = which ? 1.0f : 0.125f;
    char* eb = (char*)smem;
#pragma unroll
    for (int fn = 0; fn < 4; ++fn) {
      const int nloc = wn * 64 + fn * 16 + q4 * 4;
      const f32x4 bn = *(const f32x4*)&bias[n0 + nloc];
      const int cb = nloc * 2;           // byte col, 8B aligned
      const int slot = cb >> 4;          // 16B slot 0..31
      const int half8 = cb & 15;         // 0 or 8
#pragma unroll
      for (int fm = 0; fm < 8; ++fm) {
        const int tok = wm * 128 + fm * 16 + m16;
        bf16x4 pk;
#pragma unroll
        for (int r = 0; r < 4; ++r) pk[r] = (__bf16)((acc[fm][fn][r] + bn[r]) * qscale);
        *(bf16x4*)(eb + tok * 512 + ((slot ^ (tok & 7)) << 4) + half8) = pk;
      }
    }
    __syncthreads();
    const int bi = m0 >> 8;
    const int nrel0 = n0 - which * 768;  // 0..512, multiple of 256
    __bf16* dst = (which ? kbuf : (__bf16*)out0) + (size_t)bi * 12 * 16384;
#pragma unroll
    for (int pass = 0; pass < 16; ++pass) {
      const int tokr = pass * 16 + (tid >> 5);
      const int slot = tid & 31;
      const bf16x8 vv = *(const bf16x8*)(eb + tokr * 512 + ((slot ^ (tokr & 7)) << 4));
      const int nr = nrel0 + slot * 8;  // head-aligned: (nr&63) = (slot&7)*8
      *(bf16x8*)(dst + (size_t)(nr >> 6) * 16384 + (size_t)tokr * 64 + (nr & 63)) = vv;
    }
  } else if (MODE == 2) {
    // acc (no-TRANS): C[tok][n], r -> tok, m16 -> n.
    // LDS tile: [256 n][256 tok bf16] rows of 512 B -> V^T rows stored whole.
    char* eb = (char*)smem;
#pragma unroll
    for (int fn = 0; fn < 4; ++fn) {
      const int nloc = wn * 64 + fn * 16 + m16;
      const float bn = bias[n0 + nloc];
#pragma unroll
      for (int fm = 0; fm < 8; ++fm) {
        const int tcb = (wm * 128 + fm * 16 + q4 * 4) * 2;  // tok byte col
        const int slot = tcb >> 4;
        const int half8 = tcb & 15;
        bf16x4 pk;
#pragma unroll
        for (int r = 0; r < 4; ++r) pk[r] = (__bf16)(acc[fm][fn][r] + bn);
        *(bf16x4*)(eb + nloc * 512 + ((slot ^ (nloc & 7)) << 4) + half8) = pk;
      }
    }
    __syncthreads();
    const int bi = m0 >> 8;
    __bf16* vt = (__bf16*)out0;
#pragma unroll
    for (int pass = 0; pass < 16; ++pass) {
      const int nr = pass * 16 + (tid >> 5);  // n row 0..255
      const int slot = tid & 31;
      const bf16x8 vv = *(const bf16x8*)(eb + nr * 512 + ((slot ^ (nr & 7)) << 4));
      const int ng = n0 + nr;  // 0..767 within V region
      *(bf16x8*)(vt + (((size_t)bi * 12 + (ng >> 6)) * 64 + (ng & 63)) * 256 + slot * 8) = vv;
    }
  } else {
    // acc (TRANS): C[n][tok], r -> n, m16 -> tok. fp32 out in two n-halves.
    // LDS tile per half: [256 tok][128 n fp32] rows of 512 B.
    char* ef = (char*)smem;
    float* out = (float*)out0;
#pragma unroll
    for (int half = 0; half < 2; ++half) {
      if ((wn >> 1) == half) {
#pragma unroll
        for (int fn = 0; fn < 4; ++fn) {
          const int nl = (wn & 1) * 64 + fn * 16 + q4 * 4;  // 0..127
          const f32x4 bn = *(const f32x4*)&bias[n0 + half * 128 + nl];
          const int slot = nl >> 2;  // full 16B slot per lane
#pragma unroll
          for (int fm = 0; fm < 8; ++fm) {
            const int tok = wm * 128 + fm * 16 + m16;
            f32x4 v;
#pragma unroll
            for (int r = 0; r < 4; ++r) v[r] = acc[fm][fn][r] + bn[r];
            *(f32x4*)(ef + tok * 512 + ((slot ^ (tok & 7)) << 4)) = v;
          }
        }
      }
      __syncthreads();
#pragma unroll
      for (int pass = 0; pass < 16; ++pass) {
        const int tokr = pass * 16 + (tid >> 5);
        const int slot = tid & 31;
        const f32x4 vv = *(const f32x4*)(ef + tokr * 512 + ((slot ^ (tokr & 7)) << 4));
        *(f32x4*)(out + (size_t)(m0 + tokr) * N + n0 + half * 128 + slot * 4) = vv;
      }
      __syncthreads();
    }
  }
}

// ---------------------------------------------------------------- attention
// grid (128, 12, 2): b, h, half — the two halves sharing (b,h) K/V differ by
// 1536 linear ids (=0 mod 8) -> same XCD, second half L2-hits K/V.
// block 512 = 8 waves; wave w owns 16 Q-rows. K staged in LDS (XOR swizzle);
// V^T read DIRECTLY from global (single-use data, L2-resident — staging it
// was pure overhead). P lives in a dedicated wave-private LDS region with a
// conflict-free XOR-slot swizzle (mask = (row&7) ^ ((row&8)>>2)) — the old
// stride-72 P round-trip was an 8-way read conflict (3.9M conflict cycles).
__global__ __launch_bounds__(512, 4) void attn_kernel(const __bf16* __restrict__ qb,
                                                      const __bf16* __restrict__ kb,
                                                      const __bf16* __restrict__ vtb,
                                                      const float* __restrict__ biasT,
                                                      __bf16* __restrict__ o_ws) {
  __shared__ __align__(16) __bf16 klds[256 * 64];  // 32 KB staged K
  __shared__ __align__(16) __bf16 plds[8 * 1024];  // 16 KB: per-wave 16x64 P tile
  const int tid = threadIdx.x;
  const int lane = tid & 63, w = tid >> 6;  // w in [0,8)
  const int m16 = lane & 15, q4 = lane >> 4;
  const int b = blockIdx.x, h = blockIdx.y;
  const size_t bh = (size_t)b * 12 + h;
  const __bf16* Q = qb + bh * (256 * 64);
  const __bf16* Kp = kb + bh * (256 * 64);
  const __bf16* Vt = vtb + bh * (64 * 256);
  const float* BhT = biasT + (size_t)h * 65536;
  const int qbase = blockIdx.z * 128;
  const int qrow0 = qbase + w * 16;  // this wave's 16 Q-rows

  // --- stage K: wave w covers rows [w*32, w*32+32), 4 insts x 8 rows x 128 B
#pragma unroll
  for (int i = 0; i < 4; ++i) {
    const int row = w * 32 + i * 8 + (lane >> 3);
    const int col = ((lane & 7) ^ (row & 7)) * 8;
    gload_lds16(Kp + (size_t)row * 64 + col, &klds[(w * 32 + i * 8) * 64]);
  }

  // --- Q frags (A-layout) from global, overlaps staging
  bf16x8 qf[2];
#pragma unroll
  for (int t = 0; t < 2; ++t)
    qf[t] = *(const bf16x8*)(Q + (size_t)(qrow0 + m16) * 64 + t * 32 + q4 * 8);

  __syncthreads();  // K staging complete (barrier drains vmcnt)

  // --- S = (Q*scale) K^T from LDS
  f32x4 s[16];
#pragma unroll
  for (int c = 0; c < 16; ++c) {
    const int krow = c * 16 + m16;
    const bf16x8 kf0 = *(const bf16x8*)&klds[krow * 64 + ((q4 ^ (m16 & 7)) * 8)];
    const bf16x8 kf1 = *(const bf16x8*)&klds[krow * 64 + (((4 + q4) ^ (m16 & 7)) * 8)];
    f32x4 z = {0.f, 0.f, 0.f, 0.f};
    z = MFMA16(qf[0], kf0, z);
    s[c] = MFMA16(qf[1], kf1, z);
  }

  // --- + rel-pos bias, f32x4 along the q-row dim (transposed gather layout)
#pragma unroll
  for (int c = 0; c < 16; ++c) {
    const f32x4 bv = *(const f32x4*)&BhT[(size_t)(c * 16 + m16) * 256 + qrow0 + q4 * 4];
    s[c] += bv;
  }

  // --- full-row softmax; row owned by the 16 lanes sharing q4
  float linv[4];
#pragma unroll
  for (int r = 0; r < 4; ++r) {
    float mx = s[0][r];
#pragma unroll
    for (int c = 1; c < 16; ++c) mx = fmaxf(mx, s[c][r]);
    mx = fmaxf(mx, __shfl_xor(mx, 1));
    mx = fmaxf(mx, __shfl_xor(mx, 2));
    mx = fmaxf(mx, __shfl_xor(mx, 4));
    mx = fmaxf(mx, __shfl_xor(mx, 8));
    float sum = 0.f;
#pragma unroll
    for (int c = 0; c < 16; ++c) {
      const float p = exp2f((s[c][r] - mx) * 1.4426950408889634f);
      s[c][r] = p;
      sum += p;
    }
    sum += __shfl_xor(sum, 1);
    sum += __shfl_xor(sum, 2);
    sum += __shfl_xor(sum, 4);
    sum += __shfl_xor(sum, 8);
    linv[r] = 1.f / sum;
  }

  // --- O = P V; P round-trips through this wave's private plds slice.
  // Swizzle: phys_slot = logical_slot ^ mask(row), mask = (row&7)^((row&8)>>2).
  // Write: row = q4*4+r (mask = r ^ mq); read: row = m16 (mask = rmask).
  f32x4 o[4] = {};
  __bf16* P = &plds[w * 1024];
  const int rmask = (m16 & 7) ^ ((m16 & 8) >> 2);
  const int mq = (2 * (q4 >> 1)) ^ (4 * (q4 & 1));
  const int ws8 = m16 >> 3, w7 = m16 & 7;
#pragma unroll
  for (int ch = 0; ch < 4; ++ch) {
#pragma unroll
    for (int cc = 0; cc < 4; ++cc)
#pragma unroll
      for (int r = 0; r < 4; ++r)
        P[(q4 * 4 + r) * 64 + (((cc * 2 + ws8) ^ (r ^ mq)) * 8) + w7] =
            (__bf16)s[ch * 4 + cc][r];
    // same-wave LDS RAW/WAR: compiler lgkmcnt waits, no barrier needed
#pragma unroll
    for (int kt = 0; kt < 2; ++kt) {
      const bf16x8 pf = *(const bf16x8*)(P + m16 * 64 + (((kt * 4 + q4) ^ rmask) * 8));
#pragma unroll
      for (int dt = 0; dt < 4; ++dt) {
        const bf16x8 vf = *(const bf16x8*)(Vt + (size_t)(dt * 16 + m16) * 256 +
                                           ch * 64 + kt * 32 + q4 * 8);
        o[dt] = MFMA16(pf, vf, o[dt]);
      }
    }
  }

  // --- normalize + store bf16 [b*n][h*64+d] for the out-proj GEMM
#pragma unroll
  for (int dt = 0; dt < 4; ++dt)
#pragma unroll
    for (int r = 0; r < 4; ++r) {
      const float v = o[dt][r] * linv[r];
      const size_t row = (size_t)b * 256 + qrow0 + q4 * 4 + r;
      o_ws[row * 768 + h * 64 + dt * 16 + m16] = (__bf16)v;
    }
}

// ---------------------------------------------------------------- launch
extern "C" void kernel_launch(void* const* d_in, const int* in_sizes, int n_in,
                              void* d_out, int out_size, void* d_ws, size_t ws_size,
                              hipStream_t stream) {
  const float* x = (const float*)d_in[0];      // [128,256,768]
  const float* Wqkv = (const float*)d_in[1];   // [768,2304]
  const float* bqkv = (const float*)d_in[2];   // [2304]
  const float* Wout = (const float*)d_in[3];   // [768,768]
  const float* bout = (const float*)d_in[4];   // [768]
  const float* table = (const float*)d_in[5];  // [961,12]
  const int* ids = (const int*)d_in[6];        // [65536]
  float* out = (float*)d_out;

  char* ws = (char*)d_ws;
  __bf16* xbf = (__bf16*)ws;                             // 50331648 B (alias: o_ws)
  __bf16* wqkvt = (__bf16*)(ws + 50331648);              //  3538944 B
  __bf16* woutt = (__bf16*)(ws + 53870592);              //  1179648 B
  __bf16* qbuf = (__bf16*)(ws + 55050240);               // 50331648 B
  __bf16* kbuf = (__bf16*)(ws + 105381888);              // 50331648 B
  __bf16* vtbuf = (__bf16*)(ws + 155713536);             // 50331648 B
  float* biasT = (float*)(ws + 206045184);               //  3145728 B

  conv_x_kernel<<<24576, 256, 0, stream>>>(x, xbf);
  transpose_conv_kernel<<<dim3(72, 24), dim3(32, 8), 0, stream>>>(Wqkv, wqkvt, 768, 2304);
  transpose_conv_kernel<<<dim3(24, 24), dim3(32, 8), 0, stream>>>(Wout, woutt, 768, 768);
  bias_gather_kernel<<<3072, 256, 0, stream>>>(table, ids, biasT);
  // QK part: N in [0,1536), 6 N-tiles x 128 M-tiles -> 768 blocks (256^2 tiles)
  gemm8_kernel<0, 6><<<768, 512, 0, stream>>>(xbf, wqkvt, bqkv, qbuf, kbuf,
                                              32768, 1536, 768);
  // V part: N in [1536,2304) -> V^T scatter, 3 N-tiles -> 384 blocks
  gemm8_kernel<2, 3><<<384, 512, 0, stream>>>(xbf, wqkvt + (size_t)1536 * 768,
                                              bqkv + 1536, vtbuf, nullptr,
                                              32768, 768, 768);
  attn_kernel<<<dim3(128, 12, 2), 512, 0, stream>>>(qbuf, kbuf, vtbuf, biasT, xbf /*o_ws*/);
  gemm8_kernel<1, 3><<<384, 512, 0, stream>>>(xbf, woutt, bout, out, nullptr,
                                              32768, 768, 768);
}

// Round 4
// 497.181 us; speedup vs baseline: 1.0779x; 1.0779x over previous
//
#include <hip/hip_runtime.h>
#include <cstdint>
#include <cstddef>

typedef __bf16 bf16x8 __attribute__((ext_vector_type(8)));
typedef __bf16 bf16x4 __attribute__((ext_vector_type(4)));
typedef float f32x4 __attribute__((ext_vector_type(4)));
static_assert(sizeof(bf16x8) == 16, "bf16x8 must be 16B");
static_assert(sizeof(bf16x4) == 8, "bf16x4 must be 8B");
static_assert(sizeof(f32x4) == 16, "f32x4 must be 16B");

#define MFMA16(a, b, c) __builtin_amdgcn_mfma_f32_16x16x32_bf16((a), (b), (c), 0, 0, 0)
#define SBAR() __builtin_amdgcn_s_barrier()
#define LGKM0() asm volatile("s_waitcnt lgkmcnt(0)" ::: "memory")
#define VMCNT(n_) asm volatile("s_waitcnt vmcnt(" #n_ ")" ::: "memory")

__device__ __forceinline__ void gload_lds16(const void* g, void* l) {
  __builtin_amdgcn_global_load_lds(
      (const __attribute__((address_space(1))) void*)g,
      (__attribute__((address_space(3))) void*)l, 16, 0, 0);
}

// ---------------------------------------------------------------- conv x -> bf16
__global__ __launch_bounds__(256) void conv_x_kernel(const float* __restrict__ in,
                                                     __bf16* __restrict__ out) {
  size_t i = ((size_t)blockIdx.x * 256 + threadIdx.x) * 4;
  const float4 v = *(const float4*)(in + i);
  bf16x4 pk;
  pk[0] = (__bf16)v.x;
  pk[1] = (__bf16)v.y;
  pk[2] = (__bf16)v.z;
  pk[3] = (__bf16)v.w;
  *(bf16x4*)(out + i) = pk;
}

// ------------------------------------------- transpose fp32 [K][N] -> bf16 [N][K]
__global__ __launch_bounds__(256) void transpose_conv_kernel(const float* __restrict__ in,
                                                             __bf16* __restrict__ out,
                                                             int K, int N) {
  __shared__ float tile[32][33];
  const int n0 = blockIdx.x * 32, k0 = blockIdx.y * 32;
  const int tx = threadIdx.x, ty = threadIdx.y;  // (32, 8)
#pragma unroll
  for (int i = 0; i < 4; ++i)
    tile[ty * 4 + i][tx] = in[(size_t)(k0 + ty * 4 + i) * N + n0 + tx];
  __syncthreads();
#pragma unroll
  for (int i = 0; i < 4; ++i)
    out[(size_t)(n0 + ty * 4 + i) * K + k0 + tx] = (__bf16)tile[tx][ty * 4 + i];
}

// ------------------------------------------------------- rel-pos bias gather (TRANSPOSED)
// biasT[h][j][i] = table[ids[i*256+j]*12 + h]  -> attn reads f32x4 along i
__global__ __launch_bounds__(256) void bias_gather_kernel(const float* __restrict__ table,
                                                          const int* __restrict__ ids,
                                                          float* __restrict__ biasT) {
  const int idx = blockIdx.x * 256 + threadIdx.x;  // h*65536 + j*256 + i
  const int h = idx >> 16, ji = idx & 65535;
  const int j = ji >> 8, i = ji & 255;
  biasT[idx] = table[ids[i * 256 + j] * 12 + h];
}

// ---------------------------------------------------------------- bf16 GEMM (8-phase)
// C[M,N] = A[M,K] * Bt^T. 256x256 tile, BK=64, 8 waves (2M x 4N), per-wave 128x64.
// Double-buffered 128 KiB LDS, 4 phases per K-tile, counted vmcnt (never 0 in loop),
// setprio around MFMA clusters, bijective XCD swizzle (grid % 8 == 0).
// Epilogue: acc -> LDS (slot-XOR swizzled, conflict-free) -> fully coalesced
// 16B-per-lane stores.
// MODE 0: -> packed Q(scaled)/K [b,h,tok,d]; MODE 1: -> fp32 C+bias;
// MODE 2: -> packed V^T [b,h,d,tok]
template <int MODE, int NT>
__global__ __launch_bounds__(512, 2) void gemm8_kernel(const __bf16* __restrict__ A,
                                                       const __bf16* __restrict__ Bt,
                                                       const float* __restrict__ bias,
                                                       void* __restrict__ out0,
                                                       __bf16* __restrict__ kbuf,
                                                       const int M, const int N, const int K) {
  constexpr bool TRANS = (MODE != 2);
  __shared__ __align__(16) __bf16 smem[65536];  // 128 KiB: [2 buf][A|B][256][64]
  const int tid = threadIdx.x;
  const int lane = tid & 63, w = tid >> 6;  // 8 waves
  const int m16 = lane & 15, q4 = lane >> 4;
  const int wm = w & 1, wn = w >> 1;  // 2 x 4 wave grid

  // bijective XCD swizzle: nwg % 8 == 0 for all launches here
  const int nwg = NT * (M >> 8);
  const int chunk = nwg >> 3;
  const int id = blockIdx.x;
  const int wg = (id & 7) * chunk + (id >> 3);
  const int mi = wg / NT, ni = wg - mi * NT;
  const int m0 = mi << 8, n0 = ni << 8;

  // ---- staging addressing: per-lane global src, wave-uniform LDS dst (+lane*16B in HW)
  const int srow = w * 8 + (lane >> 3);               // 0..63
  const int sg = ((lane & 7) ^ (srow & 7)) * 8;       // XOR-swizzled col group (constant)
  const __bf16* ag = A + (size_t)(m0 + srow) * K + sg;
  const __bf16* bg = Bt + (size_t)(n0 + srow) * K + sg;
  const int dstw = w * 512;

  // ---- frag-read offsets (elements); row&7 == m16&7 for all frag rows
  const int g0 = (q4 ^ (m16 & 7)) * 8;
  const int g1 = ((4 + q4) ^ (m16 & 7)) * 8;
  const int abase = (wm * 128 + m16) * 64;
  const int bbase = 16384 + (wn * 64 + m16) * 64;

  const int nt = K >> 6;  // 12 for all launches here (>= 2 required)

#define STAGE(T_, mat_, h_)                                                        \
  do {                                                                             \
    const __bf16* s_ = ((mat_) ? bg : ag) + (size_t)(T_)*64 + (size_t)(h_)*128 * K; \
    __bf16* d_ = &smem[((T_)&1) * 32768 + (mat_)*16384 + (h_)*8192 + dstw];        \
    gload_lds16(s_, d_);                                                           \
    gload_lds16(s_ + (size_t)64 * K, d_ + 4096);                                   \
  } while (0)

#define MM(a_, b_, c_) (TRANS ? MFMA16((b_), (a_), (c_)) : MFMA16((a_), (b_), (c_)))

  // ---- prologue: tile0 fully + A(1)h0; wait tile0 (leave A(1)h0 in flight)
  STAGE(0, 0, 0);
  STAGE(0, 0, 1);
  STAGE(0, 1, 0);
  STAGE(0, 1, 1);
  STAGE(1, 0, 0);
  VMCNT(2);
  SBAR();

  f32x4 acc[8][4] = {};
  for (int T = 0; T < nt; ++T) {
    const int base = (T & 1) * 32768;
    bf16x8 a[4][2], b0[2][2], b1[2][2];

    // -------- P1: quadrant (m-half0, n-half0); reads A m0 (8) + B n0 (4)
#pragma unroll
    for (int fm = 0; fm < 4; ++fm) {
      a[fm][0] = *(const bf16x8*)&smem[base + abase + fm * 1024 + g0];
      a[fm][1] = *(const bf16x8*)&smem[base + abase + fm * 1024 + g1];
    }
#pragma unroll
    for (int fn = 0; fn < 2; ++fn) {
      b0[fn][0] = *(const bf16x8*)&smem[base + bbase + fn * 1024 + g0];
      b0[fn][1] = *(const bf16x8*)&smem[base + bbase + fn * 1024 + g1];
    }
    if (T + 1 < nt) STAGE(T + 1, 0, 1);
    SBAR();
    LGKM0();
    __builtin_amdgcn_s_setprio(1);
#pragma unroll
    for (int kh = 0; kh < 2; ++kh)
#pragma unroll
      for (int fm = 0; fm < 4; ++fm)
#pragma unroll
        for (int fn = 0; fn < 2; ++fn)
          acc[fm][fn] = MM(a[fm][kh], b0[fn][kh], acc[fm][fn]);
    __builtin_amdgcn_s_setprio(0);
    SBAR();

    // -------- P2: quadrant (m0, n1); reads B n1 (4)
#pragma unroll
    for (int fn = 0; fn < 2; ++fn) {
      b1[fn][0] = *(const bf16x8*)&smem[base + bbase + 2048 + fn * 1024 + g0];
      b1[fn][1] = *(const bf16x8*)&smem[base + bbase + 2048 + fn * 1024 + g1];
    }
    if (T + 1 < nt) {
      STAGE(T + 1, 1, 0);
      STAGE(T + 1, 1, 1);
    }
    SBAR();
    LGKM0();
    __builtin_amdgcn_s_setprio(1);
#pragma unroll
    for (int kh = 0; kh < 2; ++kh)
#pragma unroll
      for (int fm = 0; fm < 4; ++fm)
#pragma unroll
        for (int fn = 0; fn < 2; ++fn)
          acc[fm][2 + fn] = MM(a[fm][kh], b1[fn][kh], acc[fm][2 + fn]);
    __builtin_amdgcn_s_setprio(0);
    SBAR();

    // -------- P3: quadrant (m1, n1); reads A m1 (8)
#pragma unroll
    for (int fm = 0; fm < 4; ++fm) {
      a[fm][0] = *(const bf16x8*)&smem[base + abase + 4096 + fm * 1024 + g0];
      a[fm][1] = *(const bf16x8*)&smem[base + abase + 4096 + fm * 1024 + g1];
    }
    SBAR();
    LGKM0();
    __builtin_amdgcn_s_setprio(1);
#pragma unroll
    for (int kh = 0; kh < 2; ++kh)
#pragma unroll
      for (int fm = 0; fm < 4; ++fm)
#pragma unroll
        for (int fn = 0; fn < 2; ++fn)
          acc[4 + fm][2 + fn] = MM(a[fm][kh], b1[fn][kh], acc[4 + fm][2 + fn]);
    __builtin_amdgcn_s_setprio(0);
    SBAR();

    // -------- P4: quadrant (m1, n0); no reads; counted vmcnt once per K-tile
    if (T + 2 < nt) {
      STAGE(T + 2, 0, 0);
      VMCNT(2);
    } else if (T + 1 < nt) {
      VMCNT(0);
    }
    SBAR();
    __builtin_amdgcn_s_setprio(1);
#pragma unroll
    for (int kh = 0; kh < 2; ++kh)
#pragma unroll
      for (int fm = 0; fm < 4; ++fm)
#pragma unroll
        for (int fn = 0; fn < 2; ++fn)
          acc[4 + fm][fn] = MM(a[fm][kh], b0[fn][kh], acc[4 + fm][fn]);
    __builtin_amdgcn_s_setprio(0);
    SBAR();
  }
#undef STAGE
#undef MM

  // ---------------- epilogue: LDS transpose -> coalesced stores
  __syncthreads();  // all loop LDS traffic retired; smem reusable

  if (MODE == 0) {
    // acc (TRANS): value C[n][tok], r -> n, m16 -> tok.
    // LDS tile: [256 tok][256 n bf16] rows of 512 B, 16B-slot s' = s ^ (tok&7).
    const int which = (n0 >= 768);
    const float qscale = which ? 1.0f : 0.125f;
    char* eb = (char*)smem;
#pragma unroll
    for (int fn = 0; fn < 4; ++fn) {
      const int nloc = wn * 64 + fn * 16 + q4 * 4;
      const f32x4 bn = *(const f32x4*)&bias[n0 + nloc];
      const int cb = nloc * 2;           // byte col, 8B aligned
      const int slot = cb >> 4;          // 16B slot 0..31
      const int half8 = cb & 15;         // 0 or 8
#pragma unroll
      for (int fm = 0; fm < 8; ++fm) {
        const int tok = wm * 128 + fm * 16 + m16;
        bf16x4 pk;
#pragma unroll
        for (int r = 0; r < 4; ++r) pk[r] = (__bf16)((acc[fm][fn][r] + bn[r]) * qscale);
        *(bf16x4*)(eb + tok * 512 + ((slot ^ (tok & 7)) << 4) + half8) = pk;
      }
    }
    __syncthreads();
    const int bi = m0 >> 8;
    const int nrel0 = n0 - which * 768;  // 0..512, multiple of 256
    __bf16* dst = (which ? kbuf : (__bf16*)out0) + (size_t)bi * 12 * 16384;
#pragma unroll
    for (int pass = 0; pass < 16; ++pass) {
      const int tokr = pass * 16 + (tid >> 5);
      const int slot = tid & 31;
      const bf16x8 vv = *(const bf16x8*)(eb + tokr * 512 + ((slot ^ (tokr & 7)) << 4));
      const int nr = nrel0 + slot * 8;  // head-aligned: (nr&63) = (slot&7)*8
      *(bf16x8*)(dst + (size_t)(nr >> 6) * 16384 + (size_t)tokr * 64 + (nr & 63)) = vv;
    }
  } else if (MODE == 2) {
    // acc (no-TRANS): C[tok][n], r -> tok, m16 -> n.
    // LDS tile: [256 n][256 tok bf16] rows of 512 B -> V^T rows stored whole.
    char* eb = (char*)smem;
#pragma unroll
    for (int fn = 0; fn < 4; ++fn) {
      const int nloc = wn * 64 + fn * 16 + m16;
      const float bn = bias[n0 + nloc];
#pragma unroll
      for (int fm = 0; fm < 8; ++fm) {
        const int tcb = (wm * 128 + fm * 16 + q4 * 4) * 2;  // tok byte col
        const int slot = tcb >> 4;
        const int half8 = tcb & 15;
        bf16x4 pk;
#pragma unroll
        for (int r = 0; r < 4; ++r) pk[r] = (__bf16)(acc[fm][fn][r] + bn);
        *(bf16x4*)(eb + nloc * 512 + ((slot ^ (nloc & 7)) << 4) + half8) = pk;
      }
    }
    __syncthreads();
    const int bi = m0 >> 8;
    __bf16* vt = (__bf16*)out0;
#pragma unroll
    for (int pass = 0; pass < 16; ++pass) {
      const int nr = pass * 16 + (tid >> 5);  // n row 0..255
      const int slot = tid & 31;
      const bf16x8 vv = *(const bf16x8*)(eb + nr * 512 + ((slot ^ (nr & 7)) << 4));
      const int ng = n0 + nr;  // 0..767 within V region
      *(bf16x8*)(vt + (((size_t)bi * 12 + (ng >> 6)) * 64 + (ng & 63)) * 256 + slot * 8) = vv;
    }
  } else {
    // acc (TRANS): C[n][tok], r -> n, m16 -> tok. fp32 out in two n-halves.
    // LDS tile per half: [256 tok][128 n fp32] rows of 512 B.
    char* ef = (char*)smem;
    float* out = (float*)out0;
#pragma unroll
    for (int half = 0; half < 2; ++half) {
      if ((wn >> 1) == half) {
#pragma unroll
        for (int fn = 0; fn < 4; ++fn) {
          const int nl = (wn & 1) * 64 + fn * 16 + q4 * 4;  // 0..127
          const f32x4 bn = *(const f32x4*)&bias[n0 + half * 128 + nl];
          const int slot = nl >> 2;  // full 16B slot per lane
#pragma unroll
          for (int fm = 0; fm < 8; ++fm) {
            const int tok = wm * 128 + fm * 16 + m16;
            f32x4 v;
#pragma unroll
            for (int r = 0; r < 4; ++r) v[r] = acc[fm][fn][r] + bn[r];
            *(f32x4*)(ef + tok * 512 + ((slot ^ (tok & 7)) << 4)) = v;
          }
        }
      }
      __syncthreads();
#pragma unroll
      for (int pass = 0; pass < 16; ++pass) {
        const int tokr = pass * 16 + (tid >> 5);
        const int slot = tid & 31;
        const f32x4 vv = *(const f32x4*)(ef + tokr * 512 + ((slot ^ (tokr & 7)) << 4));
        *(f32x4*)(out + (size_t)(m0 + tokr) * N + n0 + half * 128 + slot * 4) = vv;
      }
      __syncthreads();
    }
  }
}

// ---------------------------------------------------------------- attention
// grid (128, 12, 2): b, h, half — the two halves sharing (b,h) K/V differ by
// 1536 linear ids (=0 mod 8) -> same XCD, second half L2-hits K/V.
// block 512 = 8 waves; wave w owns 16 Q-rows. K and V^T staged in LDS
// (XOR-group swizzle) — V global-direct was tried and regressed 1.6x (V latency
// lands in the PV dep chain; LDS staging hides it under S-phase+softmax).
// P round-trips through the K region (after WAR barrier) with a conflict-free
// XOR-slot swizzle (mask=(row&7)^((row&8)>>2)) — the old stride-72 layout was
// an 8-way read conflict. setprio(1) around MFMA clusters (T5, attn-positive).
__global__ __launch_bounds__(512, 4) void attn_kernel(const __bf16* __restrict__ qb,
                                                      const __bf16* __restrict__ kb,
                                                      const __bf16* __restrict__ vtb,
                                                      const float* __restrict__ biasT,
                                                      __bf16* __restrict__ o_ws) {
  __shared__ __align__(16) __bf16 klds[256 * 64];  // 32 KB, reused for P after S
  __shared__ __align__(16) __bf16 vlds[64 * 256];  // 32 KB
  const int tid = threadIdx.x;
  const int lane = tid & 63, w = tid >> 6;  // w in [0,8)
  const int m16 = lane & 15, q4 = lane >> 4;
  const int b = blockIdx.x, h = blockIdx.y;
  const size_t bh = (size_t)b * 12 + h;
  const __bf16* Q = qb + bh * (256 * 64);
  const __bf16* Kp = kb + bh * (256 * 64);
  const __bf16* Vt = vtb + bh * (64 * 256);
  const float* BhT = biasT + (size_t)h * 65536;
  const int qbase = blockIdx.z * 128;
  const int qrow0 = qbase + w * 16;  // this wave's 16 Q-rows

  // --- stage K: wave w covers rows [w*32, w*32+32), 4 insts x 8 rows x 128 B
#pragma unroll
  for (int i = 0; i < 4; ++i) {
    const int row = w * 32 + i * 8 + (lane >> 3);
    const int col = ((lane & 7) ^ (row & 7)) * 8;
    gload_lds16(Kp + (size_t)row * 64 + col, &klds[(w * 32 + i * 8) * 64]);
  }
  // --- stage V^T: wave w covers rows [w*8, w*8+8), 4 insts x 2 rows x 512 B
#pragma unroll
  for (int i = 0; i < 4; ++i) {
    const int row = w * 8 + i * 2 + (lane >> 5);
    const int g = lane & 31;
    const int gp = (g & 24) | ((g & 7) ^ (row & 7));
    gload_lds16(Vt + (size_t)row * 256 + gp * 8, &vlds[(w * 8 + i * 2) * 256]);
  }

  // --- Q frags (A-layout) from global, overlaps staging
  bf16x8 qf[2];
#pragma unroll
  for (int t = 0; t < 2; ++t)
    qf[t] = *(const bf16x8*)(Q + (size_t)(qrow0 + m16) * 64 + t * 32 + q4 * 8);

  __syncthreads();  // staging complete (barrier drains vmcnt)

  // --- S = (Q*scale) K^T from LDS
  f32x4 s[16];
  __builtin_amdgcn_s_setprio(1);
#pragma unroll
  for (int c = 0; c < 16; ++c) {
    const int krow = c * 16 + m16;
    const bf16x8 kf0 = *(const bf16x8*)&klds[krow * 64 + ((q4 ^ (m16 & 7)) * 8)];
    const bf16x8 kf1 = *(const bf16x8*)&klds[krow * 64 + (((4 + q4) ^ (m16 & 7)) * 8)];
    f32x4 z = {0.f, 0.f, 0.f, 0.f};
    z = MFMA16(qf[0], kf0, z);
    s[c] = MFMA16(qf[1], kf1, z);
  }
  __builtin_amdgcn_s_setprio(0);

  // --- + rel-pos bias, f32x4 along the q-row dim (transposed gather layout)
#pragma unroll
  for (int c = 0; c < 16; ++c) {
    const f32x4 bv = *(const f32x4*)&BhT[(size_t)(c * 16 + m16) * 256 + qrow0 + q4 * 4];
    s[c] += bv;
  }

  // --- full-row softmax; row owned by the 16 lanes sharing q4
  float linv[4];
#pragma unroll
  for (int r = 0; r < 4; ++r) {
    float mx = s[0][r];
#pragma unroll
    for (int c = 1; c < 16; ++c) mx = fmaxf(mx, s[c][r]);
    mx = fmaxf(mx, __shfl_xor(mx, 1));
    mx = fmaxf(mx, __shfl_xor(mx, 2));
    mx = fmaxf(mx, __shfl_xor(mx, 4));
    mx = fmaxf(mx, __shfl_xor(mx, 8));
    float sum = 0.f;
#pragma unroll
    for (int c = 0; c < 16; ++c) {
      const float p = exp2f((s[c][r] - mx) * 1.4426950408889634f);
      s[c][r] = p;
      sum += p;
    }
    sum += __shfl_xor(sum, 1);
    sum += __shfl_xor(sum, 2);
    sum += __shfl_xor(sum, 4);
    sum += __shfl_xor(sum, 8);
    linv[r] = 1.f / sum;
  }

  __syncthreads();  // all K ds_reads done before P overwrites the K region

  // --- O = P V; P round-trips through this wave's private klds slice.
  // Swizzle: phys_slot = logical_slot ^ mask(row), mask = (row&7)^((row&8)>>2).
  // Write: row = q4*4+r (mask = r ^ mq); read: row = m16 (mask = rmask).
  f32x4 o[4] = {};
  __bf16* P = &klds[w * 1024];  // 16 rows x 64 elems, swizzled slots
  const int rmask = (m16 & 7) ^ ((m16 & 8) >> 2);
  const int mq = (2 * (q4 >> 1)) ^ (4 * (q4 & 1));
  const int ws8 = m16 >> 3, w7 = m16 & 7;
#pragma unroll
  for (int ch = 0; ch < 4; ++ch) {
#pragma unroll
    for (int cc = 0; cc < 4; ++cc)
#pragma unroll
      for (int r = 0; r < 4; ++r)
        P[(q4 * 4 + r) * 64 + (((cc * 2 + ws8) ^ (r ^ mq)) * 8) + w7] =
            (__bf16)s[ch * 4 + cc][r];
    // same-wave LDS RAW/WAR: compiler lgkmcnt waits, no barrier needed
    __builtin_amdgcn_s_setprio(1);
#pragma unroll
    for (int kt = 0; kt < 2; ++kt) {
      const bf16x8 pf = *(const bf16x8*)(P + m16 * 64 + (((kt * 4 + q4) ^ rmask) * 8));
#pragma unroll
      for (int dt = 0; dt < 4; ++dt) {
        const int vrow = dt * 16 + m16;
        const bf16x8 vf = *(const bf16x8*)&vlds[vrow * 256 + ch * 64 +
                                                (((kt * 4 + q4) ^ (m16 & 7)) * 8)];
        o[dt] = MFMA16(pf, vf, o[dt]);
      }
    }
    __builtin_amdgcn_s_setprio(0);
  }

  // --- normalize + store bf16 [b*n][h*64+d] for the out-proj GEMM
#pragma unroll
  for (int dt = 0; dt < 4; ++dt)
#pragma unroll
    for (int r = 0; r < 4; ++r) {
      const float v = o[dt][r] * linv[r];
      const size_t row = (size_t)b * 256 + qrow0 + q4 * 4 + r;
      o_ws[row * 768 + h * 64 + dt * 16 + m16] = (__bf16)v;
    }
}

// ---------------------------------------------------------------- launch
extern "C" void kernel_launch(void* const* d_in, const int* in_sizes, int n_in,
                              void* d_out, int out_size, void* d_ws, size_t ws_size,
                              hipStream_t stream) {
  const float* x = (const float*)d_in[0];      // [128,256,768]
  const float* Wqkv = (const float*)d_in[1];   // [768,2304]
  const float* bqkv = (const float*)d_in[2];   // [2304]
  const float* Wout = (const float*)d_in[3];   // [768,768]
  const float* bout = (const float*)d_in[4];   // [768]
  const float* table = (const float*)d_in[5];  // [961,12]
  const int* ids = (const int*)d_in[6];        // [65536]
  float* out = (float*)d_out;

  char* ws = (char*)d_ws;
  __bf16* xbf = (__bf16*)ws;                             // 50331648 B (alias: o_ws)
  __bf16* wqkvt = (__bf16*)(ws + 50331648);              //  3538944 B
  __bf16* woutt = (__bf16*)(ws + 53870592);              //  1179648 B
  __bf16* qbuf = (__bf16*)(ws + 55050240);               // 50331648 B
  __bf16* kbuf = (__bf16*)(ws + 105381888);              // 50331648 B
  __bf16* vtbuf = (__bf16*)(ws + 155713536);             // 50331648 B
  float* biasT = (float*)(ws + 206045184);               //  3145728 B

  conv_x_kernel<<<24576, 256, 0, stream>>>(x, xbf);
  transpose_conv_kernel<<<dim3(72, 24), dim3(32, 8), 0, stream>>>(Wqkv, wqkvt, 768, 2304);
  transpose_conv_kernel<<<dim3(24, 24), dim3(32, 8), 0, stream>>>(Wout, woutt, 768, 768);
  bias_gather_kernel<<<3072, 256, 0, stream>>>(table, ids, biasT);
  // QK part: N in [0,1536), 6 N-tiles x 128 M-tiles -> 768 blocks (256^2 tiles)
  gemm8_kernel<0, 6><<<768, 512, 0, stream>>>(xbf, wqkvt, bqkv, qbuf, kbuf,
                                              32768, 1536, 768);
  // V part: N in [1536,2304) -> V^T scatter, 3 N-tiles -> 384 blocks
  gemm8_kernel<2, 3><<<384, 512, 0, stream>>>(xbf, wqkvt + (size_t)1536 * 768,
                                              bqkv + 1536, vtbuf, nullptr,
                                              32768, 768, 768);
  attn_kernel<<<dim3(128, 12, 2), 512, 0, stream>>>(qbuf, kbuf, vtbuf, biasT, xbf /*o_ws*/);
  gemm8_kernel<1, 3><<<384, 512, 0, stream>>>(xbf, woutt, bout, out, nullptr,
                                              32768, 768, 768);
}

// Round 5
// 485.544 us; speedup vs baseline: 1.1037x; 1.0240x over previous
//
#include <hip/hip_runtime.h>
#include <cstdint>
#include <cstddef>

typedef __bf16 bf16x8 __attribute__((ext_vector_type(8)));
typedef __bf16 bf16x4 __attribute__((ext_vector_type(4)));
typedef float f32x4 __attribute__((ext_vector_type(4)));
static_assert(sizeof(bf16x8) == 16, "bf16x8 must be 16B");
static_assert(sizeof(bf16x4) == 8, "bf16x4 must be 8B");
static_assert(sizeof(f32x4) == 16, "f32x4 must be 16B");

#define MFMA16(a, b, c) __builtin_amdgcn_mfma_f32_16x16x32_bf16((a), (b), (c), 0, 0, 0)
#define SBAR() __builtin_amdgcn_s_barrier()
#define LGKM0() asm volatile("s_waitcnt lgkmcnt(0)" ::: "memory")
#define VMCNT(n_) asm volatile("s_waitcnt vmcnt(" #n_ ")" ::: "memory")

__device__ __forceinline__ void gload_lds16(const void* g, void* l) {
  __builtin_amdgcn_global_load_lds(
      (const __attribute__((address_space(1))) void*)g,
      (__attribute__((address_space(3))) void*)l, 16, 0, 0);
}

// ---------------------------------------------------------------- conv x -> bf16
__global__ __launch_bounds__(256) void conv_x_kernel(const float* __restrict__ in,
                                                     __bf16* __restrict__ out) {
  size_t i = ((size_t)blockIdx.x * 256 + threadIdx.x) * 4;
  const float4 v = *(const float4*)(in + i);
  bf16x4 pk;
  pk[0] = (__bf16)v.x;
  pk[1] = (__bf16)v.y;
  pk[2] = (__bf16)v.z;
  pk[3] = (__bf16)v.w;
  *(bf16x4*)(out + i) = pk;
}

// ------------------------------------------- transpose fp32 [K][N] -> bf16 [N][K]
__global__ __launch_bounds__(256) void transpose_conv_kernel(const float* __restrict__ in,
                                                             __bf16* __restrict__ out,
                                                             int K, int N) {
  __shared__ float tile[32][33];
  const int n0 = blockIdx.x * 32, k0 = blockIdx.y * 32;
  const int tx = threadIdx.x, ty = threadIdx.y;  // (32, 8)
#pragma unroll
  for (int i = 0; i < 4; ++i)
    tile[ty * 4 + i][tx] = in[(size_t)(k0 + ty * 4 + i) * N + n0 + tx];
  __syncthreads();
#pragma unroll
  for (int i = 0; i < 4; ++i)
    out[(size_t)(n0 + ty * 4 + i) * K + k0 + tx] = (__bf16)tile[tx][ty * 4 + i];
}

// ------------------------------------------------------- rel-pos bias gather (TRANSPOSED)
// biasT[h][j][i] = table[ids[i*256+j]*12 + h]  -> attn reads f32x4 along i
__global__ __launch_bounds__(256) void bias_gather_kernel(const float* __restrict__ table,
                                                          const int* __restrict__ ids,
                                                          float* __restrict__ biasT) {
  const int idx = blockIdx.x * 256 + threadIdx.x;  // h*65536 + j*256 + i
  const int h = idx >> 16, ji = idx & 65535;
  const int j = ji >> 8, i = ji & 255;
  biasT[idx] = table[ids[i * 256 + j] * 12 + h];
}

// ---------------------------------------------------------------- bf16 GEMM (8-phase)
// C[M,N] = A[M,K] * Bt^T. 256x256 tile, BK=64, 8 waves (2M x 4N), per-wave 128x64.
// Double-buffered 128 KiB LDS, 4 phases per K-tile, counted vmcnt (never 0 in loop),
// setprio around MFMA clusters, bijective XCD swizzle (grid % 8 == 0).
// Epilogue: acc -> LDS (slot-XOR swizzled, conflict-free) -> fully coalesced
// 16B-per-lane stores.
// MODE 0: -> packed Q(scaled)/K [b,h,tok,d]; MODE 1: -> fp32 C+bias;
// MODE 2: -> packed V^T [b,h,d,tok]
template <int MODE, int NT>
__global__ __launch_bounds__(512, 2) void gemm8_kernel(const __bf16* __restrict__ A,
                                                       const __bf16* __restrict__ Bt,
                                                       const float* __restrict__ bias,
                                                       void* __restrict__ out0,
                                                       __bf16* __restrict__ kbuf,
                                                       const int M, const int N, const int K) {
  constexpr bool TRANS = (MODE != 2);
  __shared__ __align__(16) __bf16 smem[65536];  // 128 KiB: [2 buf][A|B][256][64]
  const int tid = threadIdx.x;
  const int lane = tid & 63, w = tid >> 6;  // 8 waves
  const int m16 = lane & 15, q4 = lane >> 4;
  const int wm = w & 1, wn = w >> 1;  // 2 x 4 wave grid

  // bijective XCD swizzle: nwg % 8 == 0 for all launches here
  const int nwg = NT * (M >> 8);
  const int chunk = nwg >> 3;
  const int id = blockIdx.x;
  const int wg = (id & 7) * chunk + (id >> 3);
  const int mi = wg / NT, ni = wg - mi * NT;
  const int m0 = mi << 8, n0 = ni << 8;

  // ---- staging addressing: per-lane global src, wave-uniform LDS dst (+lane*16B in HW)
  const int srow = w * 8 + (lane >> 3);               // 0..63
  const int sg = ((lane & 7) ^ (srow & 7)) * 8;       // XOR-swizzled col group (constant)
  const __bf16* ag = A + (size_t)(m0 + srow) * K + sg;
  const __bf16* bg = Bt + (size_t)(n0 + srow) * K + sg;
  const int dstw = w * 512;

  // ---- frag-read offsets (elements); row&7 == m16&7 for all frag rows
  const int g0 = (q4 ^ (m16 & 7)) * 8;
  const int g1 = ((4 + q4) ^ (m16 & 7)) * 8;
  const int abase = (wm * 128 + m16) * 64;
  const int bbase = 16384 + (wn * 64 + m16) * 64;

  const int nt = K >> 6;  // 12 for all launches here (>= 2 required)

#define STAGE(T_, mat_, h_)                                                        \
  do {                                                                             \
    const __bf16* s_ = ((mat_) ? bg : ag) + (size_t)(T_)*64 + (size_t)(h_)*128 * K; \
    __bf16* d_ = &smem[((T_)&1) * 32768 + (mat_)*16384 + (h_)*8192 + dstw];        \
    gload_lds16(s_, d_);                                                           \
    gload_lds16(s_ + (size_t)64 * K, d_ + 4096);                                   \
  } while (0)

#define MM(a_, b_, c_) (TRANS ? MFMA16((b_), (a_), (c_)) : MFMA16((a_), (b_), (c_)))

  // ---- prologue: tile0 fully + A(1)h0; wait tile0 (leave A(1)h0 in flight)
  STAGE(0, 0, 0);
  STAGE(0, 0, 1);
  STAGE(0, 1, 0);
  STAGE(0, 1, 1);
  STAGE(1, 0, 0);
  VMCNT(2);
  SBAR();

  f32x4 acc[8][4] = {};
  for (int T = 0; T < nt; ++T) {
    const int base = (T & 1) * 32768;
    bf16x8 a[4][2], b0[2][2], b1[2][2];

    // -------- P1: quadrant (m-half0, n-half0); reads A m0 (8) + B n0 (4)
#pragma unroll
    for (int fm = 0; fm < 4; ++fm) {
      a[fm][0] = *(const bf16x8*)&smem[base + abase + fm * 1024 + g0];
      a[fm][1] = *(const bf16x8*)&smem[base + abase + fm * 1024 + g1];
    }
#pragma unroll
    for (int fn = 0; fn < 2; ++fn) {
      b0[fn][0] = *(const bf16x8*)&smem[base + bbase + fn * 1024 + g0];
      b0[fn][1] = *(const bf16x8*)&smem[base + bbase + fn * 1024 + g1];
    }
    if (T + 1 < nt) STAGE(T + 1, 0, 1);
    SBAR();
    LGKM0();
    __builtin_amdgcn_s_setprio(1);
#pragma unroll
    for (int kh = 0; kh < 2; ++kh)
#pragma unroll
      for (int fm = 0; fm < 4; ++fm)
#pragma unroll
        for (int fn = 0; fn < 2; ++fn)
          acc[fm][fn] = MM(a[fm][kh], b0[fn][kh], acc[fm][fn]);
    __builtin_amdgcn_s_setprio(0);
    SBAR();

    // -------- P2: quadrant (m0, n1); reads B n1 (4)
#pragma unroll
    for (int fn = 0; fn < 2; ++fn) {
      b1[fn][0] = *(const bf16x8*)&smem[base + bbase + 2048 + fn * 1024 + g0];
      b1[fn][1] = *(const bf16x8*)&smem[base + bbase + 2048 + fn * 1024 + g1];
    }
    if (T + 1 < nt) {
      STAGE(T + 1, 1, 0);
      STAGE(T + 1, 1, 1);
    }
    SBAR();
    LGKM0();
    __builtin_amdgcn_s_setprio(1);
#pragma unroll
    for (int kh = 0; kh < 2; ++kh)
#pragma unroll
      for (int fm = 0; fm < 4; ++fm)
#pragma unroll
        for (int fn = 0; fn < 2; ++fn)
          acc[fm][2 + fn] = MM(a[fm][kh], b1[fn][kh], acc[fm][2 + fn]);
    __builtin_amdgcn_s_setprio(0);
    SBAR();

    // -------- P3: quadrant (m1, n1); reads A m1 (8)
#pragma unroll
    for (int fm = 0; fm < 4; ++fm) {
      a[fm][0] = *(const bf16x8*)&smem[base + abase + 4096 + fm * 1024 + g0];
      a[fm][1] = *(const bf16x8*)&smem[base + abase + 4096 + fm * 1024 + g1];
    }
    SBAR();
    LGKM0();
    __builtin_amdgcn_s_setprio(1);
#pragma unroll
    for (int kh = 0; kh < 2; ++kh)
#pragma unroll
      for (int fm = 0; fm < 4; ++fm)
#pragma unroll
        for (int fn = 0; fn < 2; ++fn)
          acc[4 + fm][2 + fn] = MM(a[fm][kh], b1[fn][kh], acc[4 + fm][2 + fn]);
    __builtin_amdgcn_s_setprio(0);
    SBAR();

    // -------- P4: quadrant (m1, n0); no reads; counted vmcnt once per K-tile
    if (T + 2 < nt) {
      STAGE(T + 2, 0, 0);
      VMCNT(2);
    } else if (T + 1 < nt) {
      VMCNT(0);
    }
    SBAR();
    __builtin_amdgcn_s_setprio(1);
#pragma unroll
    for (int kh = 0; kh < 2; ++kh)
#pragma unroll
      for (int fm = 0; fm < 4; ++fm)
#pragma unroll
        for (int fn = 0; fn < 2; ++fn)
          acc[4 + fm][fn] = MM(a[fm][kh], b0[fn][kh], acc[4 + fm][fn]);
    __builtin_amdgcn_s_setprio(0);
    SBAR();
  }
#undef STAGE
#undef MM

  // ---------------- epilogue: LDS transpose -> coalesced stores
  __syncthreads();  // all loop LDS traffic retired; smem reusable

  if (MODE == 0) {
    // acc (TRANS): value C[n][tok], r -> n, m16 -> tok.
    // LDS tile: [256 tok][256 n bf16] rows of 512 B, 16B-slot s' = s ^ (tok&7).
    const int which = (n0 >= 768);
    const float qscale = which ? 1.0f : 0.125f;
    char* eb = (char*)smem;
#pragma unroll
    for (int fn = 0; fn < 4; ++fn) {
      const int nloc = wn * 64 + fn * 16 + q4 * 4;
      const f32x4 bn = *(const f32x4*)&bias[n0 + nloc];
      const int cb = nloc * 2;           // byte col, 8B aligned
      const int slot = cb >> 4;          // 16B slot 0..31
      const int half8 = cb & 15;         // 0 or 8
#pragma unroll
      for (int fm = 0; fm < 8; ++fm) {
        const int tok = wm * 128 + fm * 16 + m16;
        bf16x4 pk;
#pragma unroll
        for (int r = 0; r < 4; ++r) pk[r] = (__bf16)((acc[fm][fn][r] + bn[r]) * qscale);
        *(bf16x4*)(eb + tok * 512 + ((slot ^ (tok & 7)) << 4) + half8) = pk;
      }
    }
    __syncthreads();
    const int bi = m0 >> 8;
    const int nrel0 = n0 - which * 768;  // 0..512, multiple of 256
    __bf16* dst = (which ? kbuf : (__bf16*)out0) + (size_t)bi * 12 * 16384;
#pragma unroll
    for (int pass = 0; pass < 16; ++pass) {
      const int tokr = pass * 16 + (tid >> 5);
      const int slot = tid & 31;
      const bf16x8 vv = *(const bf16x8*)(eb + tokr * 512 + ((slot ^ (tokr & 7)) << 4));
      const int nr = nrel0 + slot * 8;  // head-aligned: (nr&63) = (slot&7)*8
      *(bf16x8*)(dst + (size_t)(nr >> 6) * 16384 + (size_t)tokr * 64 + (nr & 63)) = vv;
    }
  } else if (MODE == 2) {
    // acc (no-TRANS): C[tok][n], r -> tok, m16 -> n.
    // LDS tile: [256 n][256 tok bf16] rows of 512 B -> V^T rows stored whole.
    char* eb = (char*)smem;
#pragma unroll
    for (int fn = 0; fn < 4; ++fn) {
      const int nloc = wn * 64 + fn * 16 + m16;
      const float bn = bias[n0 + nloc];
#pragma unroll
      for (int fm = 0; fm < 8; ++fm) {
        const int tcb = (wm * 128 + fm * 16 + q4 * 4) * 2;  // tok byte col
        const int slot = tcb >> 4;
        const int half8 = tcb & 15;
        bf16x4 pk;
#pragma unroll
        for (int r = 0; r < 4; ++r) pk[r] = (__bf16)(acc[fm][fn][r] + bn);
        *(bf16x4*)(eb + nloc * 512 + ((slot ^ (nloc & 7)) << 4) + half8) = pk;
      }
    }
    __syncthreads();
    const int bi = m0 >> 8;
    __bf16* vt = (__bf16*)out0;
#pragma unroll
    for (int pass = 0; pass < 16; ++pass) {
      const int nr = pass * 16 + (tid >> 5);  // n row 0..255
      const int slot = tid & 31;
      const bf16x8 vv = *(const bf16x8*)(eb + nr * 512 + ((slot ^ (nr & 7)) << 4));
      const int ng = n0 + nr;  // 0..767 within V region
      *(bf16x8*)(vt + (((size_t)bi * 12 + (ng >> 6)) * 64 + (ng & 63)) * 256 + slot * 8) = vv;
    }
  } else {
    // acc (TRANS): C[n][tok], r -> n, m16 -> tok. fp32 out in two n-halves.
    // LDS tile per half: [256 tok][128 n fp32] rows of 512 B.
    char* ef = (char*)smem;
    float* out = (float*)out0;
#pragma unroll
    for (int half = 0; half < 2; ++half) {
      if ((wn >> 1) == half) {
#pragma unroll
        for (int fn = 0; fn < 4; ++fn) {
          const int nl = (wn & 1) * 64 + fn * 16 + q4 * 4;  // 0..127
          const f32x4 bn = *(const f32x4*)&bias[n0 + half * 128 + nl];
          const int slot = nl >> 2;  // full 16B slot per lane
#pragma unroll
          for (int fm = 0; fm < 8; ++fm) {
            const int tok = wm * 128 + fm * 16 + m16;
            f32x4 v;
#pragma unroll
            for (int r = 0; r < 4; ++r) v[r] = acc[fm][fn][r] + bn[r];
            *(f32x4*)(ef + tok * 512 + ((slot ^ (tok & 7)) << 4)) = v;
          }
        }
      }
      __syncthreads();
#pragma unroll
      for (int pass = 0; pass < 16; ++pass) {
        const int tokr = pass * 16 + (tid >> 5);
        const int slot = tid & 31;
        const f32x4 vv = *(const f32x4*)(ef + tokr * 512 + ((slot ^ (tokr & 7)) << 4));
        *(f32x4*)(out + (size_t)(m0 + tokr) * N + n0 + half * 128 + slot * 4) = vv;
      }
      __syncthreads();
    }
  }
}

// ---------------------------------------------------------------- attention
// grid (128, 12, 2): b, h, half — the two halves sharing (b,h) K/V differ by
// 1536 linear ids (=0 mod 8) -> same XCD, second half L2-hits K/V.
// block 512 = 8 waves; wave w owns 16 Q-rows. K and V^T staged in LDS
// (XOR-group swizzle) — V global-direct was tried and regressed 1.6x (V latency
// lands in the PV dep chain). P lives in a DEDICATED wave-private plds region
// (conflict-free XOR-slot swizzle, verified r3) so the pre-PV WAR barrier is
// GONE: waves slip freely, one wave's softmax VALU overlaps another's MFMA.
// No setprio (r4 showed it re-phases waves -> sector-padded o_ws writebacks,
// WRITE_SIZE 49->92 MB and +12us).
__global__ __launch_bounds__(512, 4) void attn_kernel(const __bf16* __restrict__ qb,
                                                      const __bf16* __restrict__ kb,
                                                      const __bf16* __restrict__ vtb,
                                                      const float* __restrict__ biasT,
                                                      __bf16* __restrict__ o_ws) {
  __shared__ __align__(16) __bf16 klds[256 * 64];  // 32 KB staged K
  __shared__ __align__(16) __bf16 vlds[64 * 256];  // 32 KB staged V^T
  __shared__ __align__(16) __bf16 plds[8 * 1024];  // 16 KB per-wave P tiles
  const int tid = threadIdx.x;
  const int lane = tid & 63, w = tid >> 6;  // w in [0,8)
  const int m16 = lane & 15, q4 = lane >> 4;
  const int b = blockIdx.x, h = blockIdx.y;
  const size_t bh = (size_t)b * 12 + h;
  const __bf16* Q = qb + bh * (256 * 64);
  const __bf16* Kp = kb + bh * (256 * 64);
  const __bf16* Vt = vtb + bh * (64 * 256);
  const float* BhT = biasT + (size_t)h * 65536;
  const int qbase = blockIdx.z * 128;
  const int qrow0 = qbase + w * 16;  // this wave's 16 Q-rows

  // --- stage K: wave w covers rows [w*32, w*32+32), 4 insts x 8 rows x 128 B
#pragma unroll
  for (int i = 0; i < 4; ++i) {
    const int row = w * 32 + i * 8 + (lane >> 3);
    const int col = ((lane & 7) ^ (row & 7)) * 8;
    gload_lds16(Kp + (size_t)row * 64 + col, &klds[(w * 32 + i * 8) * 64]);
  }
  // --- stage V^T: wave w covers rows [w*8, w*8+8), 4 insts x 2 rows x 512 B
#pragma unroll
  for (int i = 0; i < 4; ++i) {
    const int row = w * 8 + i * 2 + (lane >> 5);
    const int g = lane & 31;
    const int gp = (g & 24) | ((g & 7) ^ (row & 7));
    gload_lds16(Vt + (size_t)row * 256 + gp * 8, &vlds[(w * 8 + i * 2) * 256]);
  }

  // --- Q frags (A-layout) from global, overlaps staging
  bf16x8 qf[2];
#pragma unroll
  for (int t = 0; t < 2; ++t)
    qf[t] = *(const bf16x8*)(Q + (size_t)(qrow0 + m16) * 64 + t * 32 + q4 * 8);

  __syncthreads();  // staging complete (barrier drains vmcnt)

  // --- S = (Q*scale) K^T from LDS
  f32x4 s[16];
#pragma unroll
  for (int c = 0; c < 16; ++c) {
    const int krow = c * 16 + m16;
    const bf16x8 kf0 = *(const bf16x8*)&klds[krow * 64 + ((q4 ^ (m16 & 7)) * 8)];
    const bf16x8 kf1 = *(const bf16x8*)&klds[krow * 64 + (((4 + q4) ^ (m16 & 7)) * 8)];
    f32x4 z = {0.f, 0.f, 0.f, 0.f};
    z = MFMA16(qf[0], kf0, z);
    s[c] = MFMA16(qf[1], kf1, z);
  }

  // --- + rel-pos bias, f32x4 along the q-row dim (transposed gather layout)
#pragma unroll
  for (int c = 0; c < 16; ++c) {
    const f32x4 bv = *(const f32x4*)&BhT[(size_t)(c * 16 + m16) * 256 + qrow0 + q4 * 4];
    s[c] += bv;
  }

  // --- full-row softmax; row owned by the 16 lanes sharing q4
  float linv[4];
#pragma unroll
  for (int r = 0; r < 4; ++r) {
    float mx = s[0][r];
#pragma unroll
    for (int c = 1; c < 16; ++c) mx = fmaxf(mx, s[c][r]);
    mx = fmaxf(mx, __shfl_xor(mx, 1));
    mx = fmaxf(mx, __shfl_xor(mx, 2));
    mx = fmaxf(mx, __shfl_xor(mx, 4));
    mx = fmaxf(mx, __shfl_xor(mx, 8));
    float sum = 0.f;
#pragma unroll
    for (int c = 0; c < 16; ++c) {
      const float p = exp2f((s[c][r] - mx) * 1.4426950408889634f);
      s[c][r] = p;
      sum += p;
    }
    sum += __shfl_xor(sum, 1);
    sum += __shfl_xor(sum, 2);
    sum += __shfl_xor(sum, 4);
    sum += __shfl_xor(sum, 8);
    linv[r] = 1.f / sum;
  }

  // --- O = P V; P round-trips through this wave's private plds slice.
  // NO barrier needed: plds is wave-private; vlds/klds are read-only now.
  // Swizzle: phys_slot = logical_slot ^ mask(row), mask = (row&7)^((row&8)>>2).
  // Write: row = q4*4+r (mask = r ^ mq); read: row = m16 (mask = rmask).
  f32x4 o[4] = {};
  __bf16* P = &plds[w * 1024];  // 16 rows x 64 elems, swizzled slots
  const int rmask = (m16 & 7) ^ ((m16 & 8) >> 2);
  const int mq = (2 * (q4 >> 1)) ^ (4 * (q4 & 1));
  const int ws8 = m16 >> 3, w7 = m16 & 7;
#pragma unroll
  for (int ch = 0; ch < 4; ++ch) {
#pragma unroll
    for (int cc = 0; cc < 4; ++cc)
#pragma unroll
      for (int r = 0; r < 4; ++r)
        P[(q4 * 4 + r) * 64 + (((cc * 2 + ws8) ^ (r ^ mq)) * 8) + w7] =
            (__bf16)s[ch * 4 + cc][r];
    // same-wave LDS RAW/WAR: compiler lgkmcnt waits, no barrier needed
#pragma unroll
    for (int kt = 0; kt < 2; ++kt) {
      const bf16x8 pf = *(const bf16x8*)(P + m16 * 64 + (((kt * 4 + q4) ^ rmask) * 8));
#pragma unroll
      for (int dt = 0; dt < 4; ++dt) {
        const int vrow = dt * 16 + m16;
        const bf16x8 vf = *(const bf16x8*)&vlds[vrow * 256 + ch * 64 +
                                                (((kt * 4 + q4) ^ (m16 & 7)) * 8)];
        o[dt] = MFMA16(pf, vf, o[dt]);
      }
    }
  }

  // --- normalize + store bf16 [b*n][h*64+d] for the out-proj GEMM
#pragma unroll
  for (int dt = 0; dt < 4; ++dt)
#pragma unroll
    for (int r = 0; r < 4; ++r) {
      const float v = o[dt][r] * linv[r];
      const size_t row = (size_t)b * 256 + qrow0 + q4 * 4 + r;
      o_ws[row * 768 + h * 64 + dt * 16 + m16] = (__bf16)v;
    }
}

// ---------------------------------------------------------------- launch
extern "C" void kernel_launch(void* const* d_in, const int* in_sizes, int n_in,
                              void* d_out, int out_size, void* d_ws, size_t ws_size,
                              hipStream_t stream) {
  const float* x = (const float*)d_in[0];      // [128,256,768]
  const float* Wqkv = (const float*)d_in[1];   // [768,2304]
  const float* bqkv = (const float*)d_in[2];   // [2304]
  const float* Wout = (const float*)d_in[3];   // [768,768]
  const float* bout = (const float*)d_in[4];   // [768]
  const float* table = (const float*)d_in[5];  // [961,12]
  const int* ids = (const int*)d_in[6];        // [65536]
  float* out = (float*)d_out;

  char* ws = (char*)d_ws;
  __bf16* xbf = (__bf16*)ws;                             // 50331648 B (alias: o_ws)
  __bf16* wqkvt = (__bf16*)(ws + 50331648);              //  3538944 B
  __bf16* woutt = (__bf16*)(ws + 53870592);              //  1179648 B
  __bf16* qbuf = (__bf16*)(ws + 55050240);               // 50331648 B
  __bf16* kbuf = (__bf16*)(ws + 105381888);              // 50331648 B
  __bf16* vtbuf = (__bf16*)(ws + 155713536);             // 50331648 B
  float* biasT = (float*)(ws + 206045184);               //  3145728 B

  conv_x_kernel<<<24576, 256, 0, stream>>>(x, xbf);
  transpose_conv_kernel<<<dim3(72, 24), dim3(32, 8), 0, stream>>>(Wqkv, wqkvt, 768, 2304);
  transpose_conv_kernel<<<dim3(24, 24), dim3(32, 8), 0, stream>>>(Wout, woutt, 768, 768);
  bias_gather_kernel<<<3072, 256, 0, stream>>>(table, ids, biasT);
  // QK part: N in [0,1536), 6 N-tiles x 128 M-tiles -> 768 blocks (256^2 tiles)
  gemm8_kernel<0, 6><<<768, 512, 0, stream>>>(xbf, wqkvt, bqkv, qbuf, kbuf,
                                              32768, 1536, 768);
  // V part: N in [1536,2304) -> V^T scatter, 3 N-tiles -> 384 blocks
  gemm8_kernel<2, 3><<<384, 512, 0, stream>>>(xbf, wqkvt + (size_t)1536 * 768,
                                              bqkv + 1536, vtbuf, nullptr,
                                              32768, 768, 768);
  attn_kernel<<<dim3(128, 12, 2), 512, 0, stream>>>(qbuf, kbuf, vtbuf, biasT, xbf /*o_ws*/);
  gemm8_kernel<1, 3><<<384, 512, 0, stream>>>(xbf, woutt, bout, out, nullptr,
                                              32768, 768, 768);
}

// Round 6
// 475.102 us; speedup vs baseline: 1.1280x; 1.0220x over previous
//
#include <hip/hip_runtime.h>
#include <cstdint>
#include <cstddef>

typedef __bf16 bf16x8 __attribute__((ext_vector_type(8)));
typedef __bf16 bf16x4 __attribute__((ext_vector_type(4)));
typedef float f32x4 __attribute__((ext_vector_type(4)));
static_assert(sizeof(bf16x8) == 16, "bf16x8 must be 16B");
static_assert(sizeof(bf16x4) == 8, "bf16x4 must be 8B");
static_assert(sizeof(f32x4) == 16, "f32x4 must be 16B");

#define MFMA16(a, b, c) __builtin_amdgcn_mfma_f32_16x16x32_bf16((a), (b), (c), 0, 0, 0)
#define SBAR() __builtin_amdgcn_s_barrier()
#define LGKM0() asm volatile("s_waitcnt lgkmcnt(0)" ::: "memory")
#define VMCNT(n_) asm volatile("s_waitcnt vmcnt(" #n_ ")" ::: "memory")

__device__ __forceinline__ void gload_lds16(const void* g, void* l) {
  __builtin_amdgcn_global_load_lds(
      (const __attribute__((address_space(1))) void*)g,
      (__attribute__((address_space(3))) void*)l, 16, 0, 0);
}

// ---------------------------------------------------------------- conv x -> bf16
__global__ __launch_bounds__(256) void conv_x_kernel(const float* __restrict__ in,
                                                     __bf16* __restrict__ out) {
  size_t i = ((size_t)blockIdx.x * 256 + threadIdx.x) * 4;
  const float4 v = *(const float4*)(in + i);
  bf16x4 pk;
  pk[0] = (__bf16)v.x;
  pk[1] = (__bf16)v.y;
  pk[2] = (__bf16)v.z;
  pk[3] = (__bf16)v.w;
  *(bf16x4*)(out + i) = pk;
}

// ------------------------------------------- transpose fp32 [K][N] -> bf16 [N][K]
__global__ __launch_bounds__(256) void transpose_conv_kernel(const float* __restrict__ in,
                                                             __bf16* __restrict__ out,
                                                             int K, int N) {
  __shared__ float tile[32][33];
  const int n0 = blockIdx.x * 32, k0 = blockIdx.y * 32;
  const int tx = threadIdx.x, ty = threadIdx.y;  // (32, 8)
#pragma unroll
  for (int i = 0; i < 4; ++i)
    tile[ty * 4 + i][tx] = in[(size_t)(k0 + ty * 4 + i) * N + n0 + tx];
  __syncthreads();
#pragma unroll
  for (int i = 0; i < 4; ++i)
    out[(size_t)(n0 + ty * 4 + i) * K + k0 + tx] = (__bf16)tile[tx][ty * 4 + i];
}

// ------------------------------------------------------- rel-pos bias gather (TRANSPOSED)
// biasT[h][j][i] = table[ids[i*256+j]*12 + h]  -> attn reads f32x4 along i
__global__ __launch_bounds__(256) void bias_gather_kernel(const float* __restrict__ table,
                                                          const int* __restrict__ ids,
                                                          float* __restrict__ biasT) {
  const int idx = blockIdx.x * 256 + threadIdx.x;  // h*65536 + j*256 + i
  const int h = idx >> 16, ji = idx & 65535;
  const int j = ji >> 8, i = ji & 255;
  biasT[idx] = table[ids[i * 256 + j] * 12 + h];
}

// ---------------------------------------------------------------- fused QKV GEMM (8-phase)
// C[M,2304] = A[M,768] * Bt^T, all-TRANS accumulation. 256x256 tile, BK=64,
// 8 waves (2M x 4N). Double-buffered 128 KiB LDS, 4 phases/K-tile, counted
// vmcnt (never 0 in loop), setprio around MFMA, bijective XCD swizzle.
// One launch covers Q, K AND V columns: per-block epilogue branch on n0.
//   n0 < 1536 : Q(scaled)/K pack -> [b,h,tok,d]   (bf16x4 vector LDS pack)
//   n0 >= 1536: V^T pack -> [b,h,d,tok]           (scalar LDS pack from TRANS acc)
// vs split G0+G2: one launch/drain boundary fewer, A (xbf) streamed once.
template <int NT>
__global__ __launch_bounds__(512, 2) void gemm8_qkv_kernel(const __bf16* __restrict__ A,
                                                           const __bf16* __restrict__ Bt,
                                                           const float* __restrict__ bias,
                                                           __bf16* __restrict__ qb,
                                                           __bf16* __restrict__ kb,
                                                           __bf16* __restrict__ vt,
                                                           const int M, const int K) {
  __shared__ __align__(16) __bf16 smem[65536];  // 128 KiB: [2 buf][A|B][256][64]
  const int tid = threadIdx.x;
  const int lane = tid & 63, w = tid >> 6;  // 8 waves
  const int m16 = lane & 15, q4 = lane >> 4;
  const int wm = w & 1, wn = w >> 1;  // 2 x 4 wave grid

  // bijective XCD swizzle: nwg % 8 == 0 (1152 here)
  const int nwg = NT * (M >> 8);
  const int chunk = nwg >> 3;
  const int id = blockIdx.x;
  const int wg = (id & 7) * chunk + (id >> 3);
  const int mi = wg / NT, ni = wg - mi * NT;
  const int m0 = mi << 8, n0 = ni << 8;

  // ---- staging addressing: per-lane global src, wave-uniform LDS dst
  const int srow = w * 8 + (lane >> 3);          // 0..63
  const int sg = ((lane & 7) ^ (srow & 7)) * 8;  // XOR-swizzled col group
  const __bf16* ag = A + (size_t)(m0 + srow) * K + sg;
  const __bf16* bg = Bt + (size_t)(n0 + srow) * K + sg;
  const int dstw = w * 512;

  // ---- frag-read offsets (elements)
  const int g0 = (q4 ^ (m16 & 7)) * 8;
  const int g1 = ((4 + q4) ^ (m16 & 7)) * 8;
  const int abase = (wm * 128 + m16) * 64;
  const int bbase = 16384 + (wn * 64 + m16) * 64;

  const int nt = K >> 6;  // 12

#define STAGE(T_, mat_, h_)                                                         \
  do {                                                                              \
    const __bf16* s_ = ((mat_) ? bg : ag) + (size_t)(T_)*64 + (size_t)(h_)*128 * K; \
    __bf16* d_ = &smem[((T_)&1) * 32768 + (mat_)*16384 + (h_)*8192 + dstw];         \
    gload_lds16(s_, d_);                                                            \
    gload_lds16(s_ + (size_t)64 * K, d_ + 4096);                                    \
  } while (0)

  // ---- prologue: tile0 fully + A(1)h0; wait tile0 (leave A(1)h0 in flight)
  STAGE(0, 0, 0);
  STAGE(0, 0, 1);
  STAGE(0, 1, 0);
  STAGE(0, 1, 1);
  STAGE(1, 0, 0);
  VMCNT(2);
  SBAR();

  f32x4 acc[8][4] = {};
  for (int T = 0; T < nt; ++T) {
    const int base = (T & 1) * 32768;
    bf16x8 a[4][2], b0[2][2], b1[2][2];

    // -------- P1: quadrant (m0, n-half0)
#pragma unroll
    for (int fm = 0; fm < 4; ++fm) {
      a[fm][0] = *(const bf16x8*)&smem[base + abase + fm * 1024 + g0];
      a[fm][1] = *(const bf16x8*)&smem[base + abase + fm * 1024 + g1];
    }
#pragma unroll
    for (int fn = 0; fn < 2; ++fn) {
      b0[fn][0] = *(const bf16x8*)&smem[base + bbase + fn * 1024 + g0];
      b0[fn][1] = *(const bf16x8*)&smem[base + bbase + fn * 1024 + g1];
    }
    if (T + 1 < nt) STAGE(T + 1, 0, 1);
    SBAR();
    LGKM0();
    __builtin_amdgcn_s_setprio(1);
#pragma unroll
    for (int kh = 0; kh < 2; ++kh)
#pragma unroll
      for (int fm = 0; fm < 4; ++fm)
#pragma unroll
        for (int fn = 0; fn < 2; ++fn)
          acc[fm][fn] = MFMA16(b0[fn][kh], a[fm][kh], acc[fm][fn]);
    __builtin_amdgcn_s_setprio(0);
    SBAR();

    // -------- P2: quadrant (m0, n1)
#pragma unroll
    for (int fn = 0; fn < 2; ++fn) {
      b1[fn][0] = *(const bf16x8*)&smem[base + bbase + 2048 + fn * 1024 + g0];
      b1[fn][1] = *(const bf16x8*)&smem[base + bbase + 2048 + fn * 1024 + g1];
    }
    if (T + 1 < nt) {
      STAGE(T + 1, 1, 0);
      STAGE(T + 1, 1, 1);
    }
    SBAR();
    LGKM0();
    __builtin_amdgcn_s_setprio(1);
#pragma unroll
    for (int kh = 0; kh < 2; ++kh)
#pragma unroll
      for (int fm = 0; fm < 4; ++fm)
#pragma unroll
        for (int fn = 0; fn < 2; ++fn)
          acc[fm][2 + fn] = MFMA16(b1[fn][kh], a[fm][kh], acc[fm][2 + fn]);
    __builtin_amdgcn_s_setprio(0);
    SBAR();

    // -------- P3: quadrant (m1, n1)
#pragma unroll
    for (int fm = 0; fm < 4; ++fm) {
      a[fm][0] = *(const bf16x8*)&smem[base + abase + 4096 + fm * 1024 + g0];
      a[fm][1] = *(const bf16x8*)&smem[base + abase + 4096 + fm * 1024 + g1];
    }
    SBAR();
    LGKM0();
    __builtin_amdgcn_s_setprio(1);
#pragma unroll
    for (int kh = 0; kh < 2; ++kh)
#pragma unroll
      for (int fm = 0; fm < 4; ++fm)
#pragma unroll
        for (int fn = 0; fn < 2; ++fn)
          acc[4 + fm][2 + fn] = MFMA16(b1[fn][kh], a[fm][kh], acc[4 + fm][2 + fn]);
    __builtin_amdgcn_s_setprio(0);
    SBAR();

    // -------- P4: quadrant (m1, n0); counted vmcnt once per K-tile
    if (T + 2 < nt) {
      STAGE(T + 2, 0, 0);
      VMCNT(2);
    } else if (T + 1 < nt) {
      VMCNT(0);
    }
    SBAR();
    __builtin_amdgcn_s_setprio(1);
#pragma unroll
    for (int kh = 0; kh < 2; ++kh)
#pragma unroll
      for (int fm = 0; fm < 4; ++fm)
#pragma unroll
        for (int fn = 0; fn < 2; ++fn)
          acc[4 + fm][fn] = MFMA16(b0[fn][kh], a[fm][kh], acc[4 + fm][fn]);
    __builtin_amdgcn_s_setprio(0);
    SBAR();
  }
#undef STAGE

  // ---------------- epilogue: LDS transpose -> coalesced stores
  __syncthreads();  // all loop LDS traffic retired; smem reusable
  const int bi = m0 >> 8;
  char* eb = (char*)smem;

  if (n0 < 1536) {
    // Q/K pack. acc: C[n][tok], r -> n, m16 -> tok.
    // LDS tile: [256 tok][256 n bf16] rows of 512 B, 16B-slot s' = s ^ (tok&7).
    const int which = (n0 >= 768);
    const float qscale = which ? 1.0f : 0.125f;
#pragma unroll
    for (int fn = 0; fn < 4; ++fn) {
      const int nloc = wn * 64 + fn * 16 + q4 * 4;
      const f32x4 bn = *(const f32x4*)&bias[n0 + nloc];
      const int cb = nloc * 2;   // byte col, 8B aligned
      const int slot = cb >> 4;  // 16B slot 0..31
      const int half8 = cb & 15; // 0 or 8
#pragma unroll
      for (int fm = 0; fm < 8; ++fm) {
        const int tok = wm * 128 + fm * 16 + m16;
        bf16x4 pk;
#pragma unroll
        for (int r = 0; r < 4; ++r) pk[r] = (__bf16)((acc[fm][fn][r] + bn[r]) * qscale);
        *(bf16x4*)(eb + tok * 512 + ((slot ^ (tok & 7)) << 4) + half8) = pk;
      }
    }
    __syncthreads();
    const int nrel0 = n0 - which * 768;  // 0..512, multiple of 256
    __bf16* dst = (which ? kb : qb) + (size_t)bi * 12 * 16384;
#pragma unroll
    for (int pass = 0; pass < 16; ++pass) {
      const int tokr = pass * 16 + (tid >> 5);
      const int slot = tid & 31;
      const bf16x8 vv = *(const bf16x8*)(eb + tokr * 512 + ((slot ^ (tokr & 7)) << 4));
      const int nr = nrel0 + slot * 8;  // head-aligned: (nr&63) = (slot&7)*8
      *(bf16x8*)(dst + (size_t)(nr >> 6) * 16384 + (size_t)tokr * 64 + (nr & 63)) = vv;
    }
  } else {
    // V^T pack from TRANS acc (r -> n, m16 -> tok): scalar b16 LDS writes into
    // [256 n][256 tok bf16] tile (rows 512 B, slot-XOR swizzle), then the same
    // fully-coalesced V^T row store as before.
#pragma unroll
    for (int fn = 0; fn < 4; ++fn)
#pragma unroll
      for (int r = 0; r < 4; ++r) {
        const int nloc = wn * 64 + fn * 16 + q4 * 4 + r;
        const float bn = bias[n0 + nloc];
#pragma unroll
        for (int fm = 0; fm < 8; ++fm) {
          const int tok = wm * 128 + fm * 16 + m16;
          const int tcb = tok * 2;
          *(__bf16*)(eb + nloc * 512 + (((tcb >> 4) ^ (nloc & 7)) << 4) + (tcb & 15)) =
              (__bf16)(acc[fm][fn][r] + bn);
        }
      }
    __syncthreads();
    const int nrel0v = n0 - 1536;  // 0..512
#pragma unroll
    for (int pass = 0; pass < 16; ++pass) {
      const int nr = pass * 16 + (tid >> 5);  // n row 0..255
      const int slot = tid & 31;
      const bf16x8 vv = *(const bf16x8*)(eb + nr * 512 + ((slot ^ (nr & 7)) << 4));
      const int ng = nrel0v + nr;  // 0..767 within V region
      *(bf16x8*)(vt + (((size_t)bi * 12 + (ng >> 6)) * 64 + (ng & 63)) * 256 + slot * 8) = vv;
    }
  }
}

// ---------------------------------------------------------------- out-proj GEMM (8-phase)
// C[M,N] fp32 = A[M,K] * Bt^T + bias. Same loop as the fused kernel; fp32
// epilogue via LDS transpose in two n-halves.
template <int NT>
__global__ __launch_bounds__(512, 2) void gemm8_out_kernel(const __bf16* __restrict__ A,
                                                           const __bf16* __restrict__ Bt,
                                                           const float* __restrict__ bias,
                                                           float* __restrict__ out,
                                                           const int M, const int N,
                                                           const int K) {
  __shared__ __align__(16) __bf16 smem[65536];  // 128 KiB
  const int tid = threadIdx.x;
  const int lane = tid & 63, w = tid >> 6;
  const int m16 = lane & 15, q4 = lane >> 4;
  const int wm = w & 1, wn = w >> 1;

  const int nwg = NT * (M >> 8);
  const int chunk = nwg >> 3;
  const int id = blockIdx.x;
  const int wg = (id & 7) * chunk + (id >> 3);
  const int mi = wg / NT, ni = wg - mi * NT;
  const int m0 = mi << 8, n0 = ni << 8;

  const int srow = w * 8 + (lane >> 3);
  const int sg = ((lane & 7) ^ (srow & 7)) * 8;
  const __bf16* ag = A + (size_t)(m0 + srow) * K + sg;
  const __bf16* bg = Bt + (size_t)(n0 + srow) * K + sg;
  const int dstw = w * 512;

  const int g0 = (q4 ^ (m16 & 7)) * 8;
  const int g1 = ((4 + q4) ^ (m16 & 7)) * 8;
  const int abase = (wm * 128 + m16) * 64;
  const int bbase = 16384 + (wn * 64 + m16) * 64;

  const int nt = K >> 6;

#define STAGE(T_, mat_, h_)                                                         \
  do {                                                                              \
    const __bf16* s_ = ((mat_) ? bg : ag) + (size_t)(T_)*64 + (size_t)(h_)*128 * K; \
    __bf16* d_ = &smem[((T_)&1) * 32768 + (mat_)*16384 + (h_)*8192 + dstw];         \
    gload_lds16(s_, d_);                                                            \
    gload_lds16(s_ + (size_t)64 * K, d_ + 4096);                                    \
  } while (0)

  STAGE(0, 0, 0);
  STAGE(0, 0, 1);
  STAGE(0, 1, 0);
  STAGE(0, 1, 1);
  STAGE(1, 0, 0);
  VMCNT(2);
  SBAR();

  f32x4 acc[8][4] = {};
  for (int T = 0; T < nt; ++T) {
    const int base = (T & 1) * 32768;
    bf16x8 a[4][2], b0[2][2], b1[2][2];

#pragma unroll
    for (int fm = 0; fm < 4; ++fm) {
      a[fm][0] = *(const bf16x8*)&smem[base + abase + fm * 1024 + g0];
      a[fm][1] = *(const bf16x8*)&smem[base + abase + fm * 1024 + g1];
    }
#pragma unroll
    for (int fn = 0; fn < 2; ++fn) {
      b0[fn][0] = *(const bf16x8*)&smem[base + bbase + fn * 1024 + g0];
      b0[fn][1] = *(const bf16x8*)&smem[base + bbase + fn * 1024 + g1];
    }
    if (T + 1 < nt) STAGE(T + 1, 0, 1);
    SBAR();
    LGKM0();
    __builtin_amdgcn_s_setprio(1);
#pragma unroll
    for (int kh = 0; kh < 2; ++kh)
#pragma unroll
      for (int fm = 0; fm < 4; ++fm)
#pragma unroll
        for (int fn = 0; fn < 2; ++fn)
          acc[fm][fn] = MFMA16(b0[fn][kh], a[fm][kh], acc[fm][fn]);
    __builtin_amdgcn_s_setprio(0);
    SBAR();

#pragma unroll
    for (int fn = 0; fn < 2; ++fn) {
      b1[fn][0] = *(const bf16x8*)&smem[base + bbase + 2048 + fn * 1024 + g0];
      b1[fn][1] = *(const bf16x8*)&smem[base + bbase + 2048 + fn * 1024 + g1];
    }
    if (T + 1 < nt) {
      STAGE(T + 1, 1, 0);
      STAGE(T + 1, 1, 1);
    }
    SBAR();
    LGKM0();
    __builtin_amdgcn_s_setprio(1);
#pragma unroll
    for (int kh = 0; kh < 2; ++kh)
#pragma unroll
      for (int fm = 0; fm < 4; ++fm)
#pragma unroll
        for (int fn = 0; fn < 2; ++fn)
          acc[fm][2 + fn] = MFMA16(b1[fn][kh], a[fm][kh], acc[fm][2 + fn]);
    __builtin_amdgcn_s_setprio(0);
    SBAR();

#pragma unroll
    for (int fm = 0; fm < 4; ++fm) {
      a[fm][0] = *(const bf16x8*)&smem[base + abase + 4096 + fm * 1024 + g0];
      a[fm][1] = *(const bf16x8*)&smem[base + abase + 4096 + fm * 1024 + g1];
    }
    SBAR();
    LGKM0();
    __builtin_amdgcn_s_setprio(1);
#pragma unroll
    for (int kh = 0; kh < 2; ++kh)
#pragma unroll
      for (int fm = 0; fm < 4; ++fm)
#pragma unroll
        for (int fn = 0; fn < 2; ++fn)
          acc[4 + fm][2 + fn] = MFMA16(b1[fn][kh], a[fm][kh], acc[4 + fm][2 + fn]);
    __builtin_amdgcn_s_setprio(0);
    SBAR();

    if (T + 2 < nt) {
      STAGE(T + 2, 0, 0);
      VMCNT(2);
    } else if (T + 1 < nt) {
      VMCNT(0);
    }
    SBAR();
    __builtin_amdgcn_s_setprio(1);
#pragma unroll
    for (int kh = 0; kh < 2; ++kh)
#pragma unroll
      for (int fm = 0; fm < 4; ++fm)
#pragma unroll
        for (int fn = 0; fn < 2; ++fn)
          acc[4 + fm][fn] = MFMA16(b0[fn][kh], a[fm][kh], acc[4 + fm][fn]);
    __builtin_amdgcn_s_setprio(0);
    SBAR();
  }
#undef STAGE

  // fp32 epilogue in two n-halves via LDS transpose
  __syncthreads();
  char* ef = (char*)smem;
#pragma unroll
  for (int half = 0; half < 2; ++half) {
    if ((wn >> 1) == half) {
#pragma unroll
      for (int fn = 0; fn < 4; ++fn) {
        const int nl = (wn & 1) * 64 + fn * 16 + q4 * 4;  // 0..127
        const f32x4 bn = *(const f32x4*)&bias[n0 + half * 128 + nl];
        const int slot = nl >> 2;
#pragma unroll
        for (int fm = 0; fm < 8; ++fm) {
          const int tok = wm * 128 + fm * 16 + m16;
          f32x4 v;
#pragma unroll
          for (int r = 0; r < 4; ++r) v[r] = acc[fm][fn][r] + bn[r];
          *(f32x4*)(ef + tok * 512 + ((slot ^ (tok & 7)) << 4)) = v;
        }
      }
    }
    __syncthreads();
#pragma unroll
    for (int pass = 0; pass < 16; ++pass) {
      const int tokr = pass * 16 + (tid >> 5);
      const int slot = tid & 31;
      const f32x4 vv = *(const f32x4*)(ef + tokr * 512 + ((slot ^ (tokr & 7)) << 4));
      *(f32x4*)(out + (size_t)(m0 + tokr) * N + n0 + half * 128 + slot * 4) = vv;
    }
    __syncthreads();
  }
}

// ---------------------------------------------------------------- attention (r2 exact)
// grid (128, 12, 2): b, h, half — the two halves sharing (b,h) K/V differ by
// 1536 linear ids (=0 mod 8) -> same XCD, second half L2-hits K/V.
// block 512 = 8 waves; wave w owns 16 Q-rows. K and V^T staged in LDS
// (XOR-group swizzle). P round-trip reuses the K LDS region after a barrier.
// (Measured: this exact structure = 101 us. P-XOR-swizzle variants, barrier
// removal, setprio, V-global-direct all regressed — r3/r4/r5.)
__global__ __launch_bounds__(512, 4) void attn_kernel(const __bf16* __restrict__ qb,
                                                      const __bf16* __restrict__ kb,
                                                      const __bf16* __restrict__ vtb,
                                                      const float* __restrict__ biasT,
                                                      __bf16* __restrict__ o_ws) {
  __shared__ __bf16 klds[256 * 64];  // 32 KB, reused for P after S-phase
  __shared__ __bf16 vlds[64 * 256];  // 32 KB
  const int tid = threadIdx.x;
  const int lane = tid & 63, w = tid >> 6;  // w in [0,8)
  const int m16 = lane & 15, q4 = lane >> 4;
  const int b = blockIdx.x, h = blockIdx.y;
  const size_t bh = (size_t)b * 12 + h;
  const __bf16* Q = qb + bh * (256 * 64);
  const __bf16* Kp = kb + bh * (256 * 64);
  const __bf16* Vt = vtb + bh * (64 * 256);
  const float* BhT = biasT + (size_t)h * 65536;
  const int qbase = blockIdx.z * 128;
  const int qrow0 = qbase + w * 16;  // this wave's 16 Q-rows

  // --- stage K: wave w covers rows [w*32, w*32+32), 4 insts x 8 rows x 128 B
#pragma unroll
  for (int i = 0; i < 4; ++i) {
    const int row = w * 32 + i * 8 + (lane >> 3);
    const int col = ((lane & 7) ^ (row & 7)) * 8;
    gload_lds16(Kp + (size_t)row * 64 + col, &klds[(w * 32 + i * 8) * 64]);
  }
  // --- stage V^T: wave w covers rows [w*8, w*8+8), 4 insts x 2 rows x 512 B
#pragma unroll
  for (int i = 0; i < 4; ++i) {
    const int row = w * 8 + i * 2 + (lane >> 5);
    const int g = lane & 31;
    const int gp = (g & 24) | ((g & 7) ^ (row & 7));
    gload_lds16(Vt + (size_t)row * 256 + gp * 8, &vlds[(w * 8 + i * 2) * 256]);
  }

  // --- Q frags (A-layout) from global, overlaps staging
  bf16x8 qf[2];
#pragma unroll
  for (int t = 0; t < 2; ++t)
    qf[t] = *(const bf16x8*)(Q + (size_t)(qrow0 + m16) * 64 + t * 32 + q4 * 8);

  __syncthreads();  // staging complete (barrier drains vmcnt)

  // --- S = (Q*scale) K^T from LDS
  f32x4 s[16];
#pragma unroll
  for (int c = 0; c < 16; ++c) {
    const int krow = c * 16 + m16;
    const bf16x8 kf0 = *(const bf16x8*)&klds[krow * 64 + ((q4 ^ (m16 & 7)) * 8)];
    const bf16x8 kf1 = *(const bf16x8*)&klds[krow * 64 + (((4 + q4) ^ (m16 & 7)) * 8)];
    f32x4 z = {0.f, 0.f, 0.f, 0.f};
    z = MFMA16(qf[0], kf0, z);
    s[c] = MFMA16(qf[1], kf1, z);
  }

  // --- + rel-pos bias, f32x4 along the q-row dim (transposed gather layout)
#pragma unroll
  for (int c = 0; c < 16; ++c) {
    const f32x4 bv = *(const f32x4*)&BhT[(size_t)(c * 16 + m16) * 256 + qrow0 + q4 * 4];
    s[c] += bv;
  }

  // --- full-row softmax; row owned by the 16 lanes sharing q4
  float linv[4];
#pragma unroll
  for (int r = 0; r < 4; ++r) {
    float mx = s[0][r];
#pragma unroll
    for (int c = 1; c < 16; ++c) mx = fmaxf(mx, s[c][r]);
    mx = fmaxf(mx, __shfl_xor(mx, 1));
    mx = fmaxf(mx, __shfl_xor(mx, 2));
    mx = fmaxf(mx, __shfl_xor(mx, 4));
    mx = fmaxf(mx, __shfl_xor(mx, 8));
    float sum = 0.f;
#pragma unroll
    for (int c = 0; c < 16; ++c) {
      const float p = exp2f((s[c][r] - mx) * 1.4426950408889634f);
      s[c][r] = p;
      sum += p;
    }
    sum += __shfl_xor(sum, 1);
    sum += __shfl_xor(sum, 2);
    sum += __shfl_xor(sum, 4);
    sum += __shfl_xor(sum, 8);
    linv[r] = 1.f / sum;
  }

  __syncthreads();  // all K ds_reads done before P overwrites the K region

  // --- O = P V; P round-trips through per-wave slice of the K region
  f32x4 o[4] = {};
  __bf16* P = &klds[w * 1152];  // 16 rows x 72 elems (16-B aligned rows)
#pragma unroll
  for (int ch = 0; ch < 4; ++ch) {
#pragma unroll
    for (int cc = 0; cc < 4; ++cc)
#pragma unroll
      for (int r = 0; r < 4; ++r)
        P[(q4 * 4 + r) * 72 + cc * 16 + m16] = (__bf16)s[ch * 4 + cc][r];
    // same-wave LDS RAW/WAR: compiler lgkmcnt waits, no barrier needed
#pragma unroll
    for (int kt = 0; kt < 2; ++kt) {
      const bf16x8 pf = *(const bf16x8*)(P + m16 * 72 + kt * 32 + q4 * 8);
#pragma unroll
      for (int dt = 0; dt < 4; ++dt) {
        const int vrow = dt * 16 + m16;
        const bf16x8 vf = *(const bf16x8*)&vlds[vrow * 256 + ch * 64 +
                                                (((kt * 4 + q4) ^ (m16 & 7)) * 8)];
        o[dt] = MFMA16(pf, vf, o[dt]);
      }
    }
  }

  // --- normalize + store bf16 [b*n][h*64+d] for the out-proj GEMM
#pragma unroll
  for (int dt = 0; dt < 4; ++dt)
#pragma unroll
    for (int r = 0; r < 4; ++r) {
      const float v = o[dt][r] * linv[r];
      const size_t row = (size_t)b * 256 + qrow0 + q4 * 4 + r;
      o_ws[row * 768 + h * 64 + dt * 16 + m16] = (__bf16)v;
    }
}

// ---------------------------------------------------------------- launch
extern "C" void kernel_launch(void* const* d_in, const int* in_sizes, int n_in,
                              void* d_out, int out_size, void* d_ws, size_t ws_size,
                              hipStream_t stream) {
  const float* x = (const float*)d_in[0];      // [128,256,768]
  const float* Wqkv = (const float*)d_in[1];   // [768,2304]
  const float* bqkv = (const float*)d_in[2];   // [2304]
  const float* Wout = (const float*)d_in[3];   // [768,768]
  const float* bout = (const float*)d_in[4];   // [768]
  const float* table = (const float*)d_in[5];  // [961,12]
  const int* ids = (const int*)d_in[6];        // [65536]
  float* out = (float*)d_out;

  char* ws = (char*)d_ws;
  __bf16* xbf = (__bf16*)ws;                             // 50331648 B (alias: o_ws)
  __bf16* wqkvt = (__bf16*)(ws + 50331648);              //  3538944 B
  __bf16* woutt = (__bf16*)(ws + 53870592);              //  1179648 B
  __bf16* qbuf = (__bf16*)(ws + 55050240);               // 50331648 B
  __bf16* kbuf = (__bf16*)(ws + 105381888);              // 50331648 B
  __bf16* vtbuf = (__bf16*)(ws + 155713536);             // 50331648 B
  float* biasT = (float*)(ws + 206045184);               //  3145728 B

  conv_x_kernel<<<24576, 256, 0, stream>>>(x, xbf);
  transpose_conv_kernel<<<dim3(72, 24), dim3(32, 8), 0, stream>>>(Wqkv, wqkvt, 768, 2304);
  transpose_conv_kernel<<<dim3(24, 24), dim3(32, 8), 0, stream>>>(Wout, woutt, 768, 768);
  bias_gather_kernel<<<3072, 256, 0, stream>>>(table, ids, biasT);
  // Fused QKV projection: N = 2304 in one launch, 9 N-tiles x 128 M-tiles
  gemm8_qkv_kernel<9><<<1152, 512, 0, stream>>>(xbf, wqkvt, bqkv, qbuf, kbuf, vtbuf,
                                                32768, 768);
  attn_kernel<<<dim3(128, 12, 2), 512, 0, stream>>>(qbuf, kbuf, vtbuf, biasT, xbf /*o_ws*/);
  gemm8_out_kernel<3><<<384, 512, 0, stream>>>(xbf, woutt, bout, out, 32768, 768, 768);
}

// Round 7
// 460.313 us; speedup vs baseline: 1.1642x; 1.0321x over previous
//
#include <hip/hip_runtime.h>
#include <cstdint>
#include <cstddef>

typedef __bf16 bf16x8 __attribute__((ext_vector_type(8)));
typedef __bf16 bf16x4 __attribute__((ext_vector_type(4)));
typedef float f32x4 __attribute__((ext_vector_type(4)));
static_assert(sizeof(bf16x8) == 16, "bf16x8 must be 16B");
static_assert(sizeof(bf16x4) == 8, "bf16x4 must be 8B");
static_assert(sizeof(f32x4) == 16, "f32x4 must be 16B");

#define MFMA16(a, b, c) __builtin_amdgcn_mfma_f32_16x16x32_bf16((a), (b), (c), 0, 0, 0)
#define SBAR() __builtin_amdgcn_s_barrier()
#define LGKM0() asm volatile("s_waitcnt lgkmcnt(0)" ::: "memory")
#define VMCNT(n_) asm volatile("s_waitcnt vmcnt(" #n_ ")" ::: "memory")

__device__ __forceinline__ void gload_lds16(const void* g, void* l) {
  __builtin_amdgcn_global_load_lds(
      (const __attribute__((address_space(1))) void*)g,
      (__attribute__((address_space(3))) void*)l, 16, 0, 0);
}

// ---------------------------------------------------------------- fused prep
// One launch replaces conv_x + 2 transposes + bias_gather (3 fewer dispatch
// gaps). Block ranges:
//   [0, 24576)        : x fp32 -> bf16 (float4 per thread)
//   [24576, 26304)    : Wqkv [768][2304] -> bf16 [2304][768]   (72 x 24 tiles)
//   [26304, 26880)    : Wout [768][768]  -> bf16 [768][768]^T  (24 x 24 tiles)
//   [26880, 29952)    : biasT[h][j][i] = table[ids[i*256+j]*12 + h]
__global__ __launch_bounds__(256) void prep_kernel(
    const float* __restrict__ x, __bf16* __restrict__ xbf,
    const float* __restrict__ Wqkv, __bf16* __restrict__ wqkvt,
    const float* __restrict__ Wout, __bf16* __restrict__ woutt,
    const float* __restrict__ table, const int* __restrict__ ids,
    float* __restrict__ biasT) {
  __shared__ float tile[32][33];
  const int bid = blockIdx.x;
  const int tid = threadIdx.x;

  if (bid < 24576) {
    size_t i = ((size_t)bid * 256 + tid) * 4;
    const float4 v = *(const float4*)(x + i);
    bf16x4 pk;
    pk[0] = (__bf16)v.x;
    pk[1] = (__bf16)v.y;
    pk[2] = (__bf16)v.z;
    pk[3] = (__bf16)v.w;
    *(bf16x4*)(xbf + i) = pk;
  } else if (bid < 26880) {
    const bool big = bid < 26304;
    const int b2 = big ? (bid - 24576) : (bid - 26304);
    const int nt = big ? 72 : 24;
    const int N = big ? 2304 : 768;
    const float* in = big ? Wqkv : Wout;
    __bf16* out = big ? wqkvt : woutt;
    const int n0 = (b2 % nt) * 32, k0 = (b2 / nt) * 32;
    const int tx = tid & 31, ty = tid >> 5;  // (32, 8)
#pragma unroll
    for (int i = 0; i < 4; ++i)
      tile[ty * 4 + i][tx] = in[(size_t)(k0 + ty * 4 + i) * N + n0 + tx];
    __syncthreads();
#pragma unroll
    for (int i = 0; i < 4; ++i)
      out[(size_t)(n0 + ty * 4 + i) * 768 + k0 + tx] = (__bf16)tile[tx][ty * 4 + i];
  } else {
    const int idx = (bid - 26880) * 256 + tid;  // h*65536 + j*256 + i
    const int h = idx >> 16, ji = idx & 65535;
    const int j = ji >> 8, i = ji & 255;
    biasT[idx] = table[ids[i * 256 + j] * 12 + h];
  }
}

// ---------------------------------------------------------------- fused QKV GEMM (8-phase)
// C[M,2304] = A[M,768] * Bt^T, all-TRANS accumulation. 256x256 tile, BK=64,
// 8 waves (2M x 4N). Double-buffered 128 KiB LDS, 4 phases/K-tile, counted
// vmcnt (never 0 in loop), setprio around MFMA, bijective XCD swizzle.
// ALL of tile T+1 is staged at P1 (target buffer is free from P1 on) for max
// latency cover; A(T+2)h0 at P4 then vmcnt(2) = tile T+1 fully landed.
// Epilogue branch on n0: Q/K pack -> [b,h,tok,d]; V^T pack -> [b,h,d,tok].
template <int NT>
__global__ __launch_bounds__(512, 2) void gemm8_qkv_kernel(const __bf16* __restrict__ A,
                                                           const __bf16* __restrict__ Bt,
                                                           const float* __restrict__ bias,
                                                           __bf16* __restrict__ qb,
                                                           __bf16* __restrict__ kb,
                                                           __bf16* __restrict__ vt,
                                                           const int M, const int K) {
  __shared__ __align__(16) __bf16 smem[65536];  // 128 KiB: [2 buf][A|B][256][64]
  const int tid = threadIdx.x;
  const int lane = tid & 63, w = tid >> 6;  // 8 waves
  const int m16 = lane & 15, q4 = lane >> 4;
  const int wm = w & 1, wn = w >> 1;  // 2 x 4 wave grid

  // bijective XCD swizzle: nwg % 8 == 0 (1152 here)
  const int nwg = NT * (M >> 8);
  const int chunk = nwg >> 3;
  const int id = blockIdx.x;
  const int wg = (id & 7) * chunk + (id >> 3);
  const int mi = wg / NT, ni = wg - mi * NT;
  const int m0 = mi << 8, n0 = ni << 8;

  // ---- staging addressing: per-lane global src, wave-uniform LDS dst
  const int srow = w * 8 + (lane >> 3);          // 0..63
  const int sg = ((lane & 7) ^ (srow & 7)) * 8;  // XOR-swizzled col group
  const __bf16* ag = A + (size_t)(m0 + srow) * K + sg;
  const __bf16* bg = Bt + (size_t)(n0 + srow) * K + sg;
  const int dstw = w * 512;

  // ---- frag-read offsets (elements)
  const int g0 = (q4 ^ (m16 & 7)) * 8;
  const int g1 = ((4 + q4) ^ (m16 & 7)) * 8;
  const int abase = (wm * 128 + m16) * 64;
  const int bbase = 16384 + (wn * 64 + m16) * 64;

  const int nt = K >> 6;  // 12

#define STAGE(T_, mat_, h_)                                                         \
  do {                                                                              \
    const __bf16* s_ = ((mat_) ? bg : ag) + (size_t)(T_)*64 + (size_t)(h_)*128 * K; \
    __bf16* d_ = &smem[((T_)&1) * 32768 + (mat_)*16384 + (h_)*8192 + dstw];         \
    gload_lds16(s_, d_);                                                            \
    gload_lds16(s_ + (size_t)64 * K, d_ + 4096);                                    \
  } while (0)

  // ---- prologue: tile0 fully + A(1)h0; wait tile0 (leave A(1)h0 in flight)
  STAGE(0, 0, 0);
  STAGE(0, 0, 1);
  STAGE(0, 1, 0);
  STAGE(0, 1, 1);
  STAGE(1, 0, 0);
  VMCNT(2);
  SBAR();

  f32x4 acc[8][4] = {};
  for (int T = 0; T < nt; ++T) {
    const int base = (T & 1) * 32768;
    bf16x8 a[4][2], b0[2][2], b1[2][2];

    // -------- P1: quadrant (m0, n-half0); stage ALL of tile T+1 remainder
#pragma unroll
    for (int fm = 0; fm < 4; ++fm) {
      a[fm][0] = *(const bf16x8*)&smem[base + abase + fm * 1024 + g0];
      a[fm][1] = *(const bf16x8*)&smem[base + abase + fm * 1024 + g1];
    }
#pragma unroll
    for (int fn = 0; fn < 2; ++fn) {
      b0[fn][0] = *(const bf16x8*)&smem[base + bbase + fn * 1024 + g0];
      b0[fn][1] = *(const bf16x8*)&smem[base + bbase + fn * 1024 + g1];
    }
    if (T + 1 < nt) {
      STAGE(T + 1, 0, 1);
      STAGE(T + 1, 1, 0);
      STAGE(T + 1, 1, 1);
    }
    SBAR();
    LGKM0();
    __builtin_amdgcn_s_setprio(1);
#pragma unroll
    for (int kh = 0; kh < 2; ++kh)
#pragma unroll
      for (int fm = 0; fm < 4; ++fm)
#pragma unroll
        for (int fn = 0; fn < 2; ++fn)
          acc[fm][fn] = MFMA16(b0[fn][kh], a[fm][kh], acc[fm][fn]);
    __builtin_amdgcn_s_setprio(0);
    SBAR();

    // -------- P2: quadrant (m0, n1)
#pragma unroll
    for (int fn = 0; fn < 2; ++fn) {
      b1[fn][0] = *(const bf16x8*)&smem[base + bbase + 2048 + fn * 1024 + g0];
      b1[fn][1] = *(const bf16x8*)&smem[base + bbase + 2048 + fn * 1024 + g1];
    }
    SBAR();
    LGKM0();
    __builtin_amdgcn_s_setprio(1);
#pragma unroll
    for (int kh = 0; kh < 2; ++kh)
#pragma unroll
      for (int fm = 0; fm < 4; ++fm)
#pragma unroll
        for (int fn = 0; fn < 2; ++fn)
          acc[fm][2 + fn] = MFMA16(b1[fn][kh], a[fm][kh], acc[fm][2 + fn]);
    __builtin_amdgcn_s_setprio(0);
    SBAR();

    // -------- P3: quadrant (m1, n1)
#pragma unroll
    for (int fm = 0; fm < 4; ++fm) {
      a[fm][0] = *(const bf16x8*)&smem[base + abase + 4096 + fm * 1024 + g0];
      a[fm][1] = *(const bf16x8*)&smem[base + abase + 4096 + fm * 1024 + g1];
    }
    SBAR();
    LGKM0();
    __builtin_amdgcn_s_setprio(1);
#pragma unroll
    for (int kh = 0; kh < 2; ++kh)
#pragma unroll
      for (int fm = 0; fm < 4; ++fm)
#pragma unroll
        for (int fn = 0; fn < 2; ++fn)
          acc[4 + fm][2 + fn] = MFMA16(b1[fn][kh], a[fm][kh], acc[4 + fm][2 + fn]);
    __builtin_amdgcn_s_setprio(0);
    SBAR();

    // -------- P4: quadrant (m1, n0); counted vmcnt once per K-tile
    if (T + 2 < nt) {
      STAGE(T + 2, 0, 0);
      VMCNT(2);
    } else if (T + 1 < nt) {
      VMCNT(0);
    }
    SBAR();
    __builtin_amdgcn_s_setprio(1);
#pragma unroll
    for (int kh = 0; kh < 2; ++kh)
#pragma unroll
      for (int fm = 0; fm < 4; ++fm)
#pragma unroll
        for (int fn = 0; fn < 2; ++fn)
          acc[4 + fm][fn] = MFMA16(b0[fn][kh], a[fm][kh], acc[4 + fm][fn]);
    __builtin_amdgcn_s_setprio(0);
    SBAR();
  }
#undef STAGE

  // ---------------- epilogue: LDS transpose -> coalesced stores
  __syncthreads();  // all loop LDS traffic retired; smem reusable
  const int bi = m0 >> 8;
  char* eb = (char*)smem;

  if (n0 < 1536) {
    // Q/K pack. acc: C[n][tok], r -> n, m16 -> tok.
    // LDS tile: [256 tok][256 n bf16] rows of 512 B, 16B-slot s' = s ^ (tok&7).
    const int which = (n0 >= 768);
    const float qscale = which ? 1.0f : 0.125f;
#pragma unroll
    for (int fn = 0; fn < 4; ++fn) {
      const int nloc = wn * 64 + fn * 16 + q4 * 4;
      const f32x4 bn = *(const f32x4*)&bias[n0 + nloc];
      const int cb = nloc * 2;   // byte col, 8B aligned
      const int slot = cb >> 4;  // 16B slot 0..31
      const int half8 = cb & 15; // 0 or 8
#pragma unroll
      for (int fm = 0; fm < 8; ++fm) {
        const int tok = wm * 128 + fm * 16 + m16;
        bf16x4 pk;
#pragma unroll
        for (int r = 0; r < 4; ++r) pk[r] = (__bf16)((acc[fm][fn][r] + bn[r]) * qscale);
        *(bf16x4*)(eb + tok * 512 + ((slot ^ (tok & 7)) << 4) + half8) = pk;
      }
    }
    __syncthreads();
    const int nrel0 = n0 - which * 768;  // 0..512, multiple of 256
    __bf16* dst = (which ? kb : qb) + (size_t)bi * 12 * 16384;
#pragma unroll
    for (int pass = 0; pass < 16; ++pass) {
      const int tokr = pass * 16 + (tid >> 5);
      const int slot = tid & 31;
      const bf16x8 vv = *(const bf16x8*)(eb + tokr * 512 + ((slot ^ (tokr & 7)) << 4));
      const int nr = nrel0 + slot * 8;  // head-aligned: (nr&63) = (slot&7)*8
      *(bf16x8*)(dst + (size_t)(nr >> 6) * 16384 + (size_t)tokr * 64 + (nr & 63)) = vv;
    }
  } else {
    // V^T pack from TRANS acc (r -> n, m16 -> tok): scalar b16 LDS writes into
    // [256 n][256 tok bf16] tile (rows 512 B, slot-XOR swizzle), then
    // fully-coalesced V^T row stores.
#pragma unroll
    for (int fn = 0; fn < 4; ++fn)
#pragma unroll
      for (int r = 0; r < 4; ++r) {
        const int nloc = wn * 64 + fn * 16 + q4 * 4 + r;
        const float bn = bias[n0 + nloc];
#pragma unroll
        for (int fm = 0; fm < 8; ++fm) {
          const int tok = wm * 128 + fm * 16 + m16;
          const int tcb = tok * 2;
          *(__bf16*)(eb + nloc * 512 + (((tcb >> 4) ^ (nloc & 7)) << 4) + (tcb & 15)) =
              (__bf16)(acc[fm][fn][r] + bn);
        }
      }
    __syncthreads();
    const int nrel0v = n0 - 1536;  // 0..512
#pragma unroll
    for (int pass = 0; pass < 16; ++pass) {
      const int nr = pass * 16 + (tid >> 5);  // n row 0..255
      const int slot = tid & 31;
      const bf16x8 vv = *(const bf16x8*)(eb + nr * 512 + ((slot ^ (nr & 7)) << 4));
      const int ng = nrel0v + nr;  // 0..767 within V region
      *(bf16x8*)(vt + (((size_t)bi * 12 + (ng >> 6)) * 64 + (ng & 63)) * 256 + slot * 8) = vv;
    }
  }
}

// ---------------------------------------------------------------- out-proj GEMM (8-phase)
// C[M,N] fp32 = A[M,K] * Bt^T + bias. Same loop; fp32 epilogue via LDS
// transpose in two n-halves.
template <int NT>
__global__ __launch_bounds__(512, 2) void gemm8_out_kernel(const __bf16* __restrict__ A,
                                                           const __bf16* __restrict__ Bt,
                                                           const float* __restrict__ bias,
                                                           float* __restrict__ out,
                                                           const int M, const int N,
                                                           const int K) {
  __shared__ __align__(16) __bf16 smem[65536];  // 128 KiB
  const int tid = threadIdx.x;
  const int lane = tid & 63, w = tid >> 6;
  const int m16 = lane & 15, q4 = lane >> 4;
  const int wm = w & 1, wn = w >> 1;

  const int nwg = NT * (M >> 8);
  const int chunk = nwg >> 3;
  const int id = blockIdx.x;
  const int wg = (id & 7) * chunk + (id >> 3);
  const int mi = wg / NT, ni = wg - mi * NT;
  const int m0 = mi << 8, n0 = ni << 8;

  const int srow = w * 8 + (lane >> 3);
  const int sg = ((lane & 7) ^ (srow & 7)) * 8;
  const __bf16* ag = A + (size_t)(m0 + srow) * K + sg;
  const __bf16* bg = Bt + (size_t)(n0 + srow) * K + sg;
  const int dstw = w * 512;

  const int g0 = (q4 ^ (m16 & 7)) * 8;
  const int g1 = ((4 + q4) ^ (m16 & 7)) * 8;
  const int abase = (wm * 128 + m16) * 64;
  const int bbase = 16384 + (wn * 64 + m16) * 64;

  const int nt = K >> 6;

#define STAGE(T_, mat_, h_)                                                         \
  do {                                                                              \
    const __bf16* s_ = ((mat_) ? bg : ag) + (size_t)(T_)*64 + (size_t)(h_)*128 * K; \
    __bf16* d_ = &smem[((T_)&1) * 32768 + (mat_)*16384 + (h_)*8192 + dstw];         \
    gload_lds16(s_, d_);                                                            \
    gload_lds16(s_ + (size_t)64 * K, d_ + 4096);                                    \
  } while (0)

  STAGE(0, 0, 0);
  STAGE(0, 0, 1);
  STAGE(0, 1, 0);
  STAGE(0, 1, 1);
  STAGE(1, 0, 0);
  VMCNT(2);
  SBAR();

  f32x4 acc[8][4] = {};
  for (int T = 0; T < nt; ++T) {
    const int base = (T & 1) * 32768;
    bf16x8 a[4][2], b0[2][2], b1[2][2];

#pragma unroll
    for (int fm = 0; fm < 4; ++fm) {
      a[fm][0] = *(const bf16x8*)&smem[base + abase + fm * 1024 + g0];
      a[fm][1] = *(const bf16x8*)&smem[base + abase + fm * 1024 + g1];
    }
#pragma unroll
    for (int fn = 0; fn < 2; ++fn) {
      b0[fn][0] = *(const bf16x8*)&smem[base + bbase + fn * 1024 + g0];
      b0[fn][1] = *(const bf16x8*)&smem[base + bbase + fn * 1024 + g1];
    }
    if (T + 1 < nt) {
      STAGE(T + 1, 0, 1);
      STAGE(T + 1, 1, 0);
      STAGE(T + 1, 1, 1);
    }
    SBAR();
    LGKM0();
    __builtin_amdgcn_s_setprio(1);
#pragma unroll
    for (int kh = 0; kh < 2; ++kh)
#pragma unroll
      for (int fm = 0; fm < 4; ++fm)
#pragma unroll
        for (int fn = 0; fn < 2; ++fn)
          acc[fm][fn] = MFMA16(b0[fn][kh], a[fm][kh], acc[fm][fn]);
    __builtin_amdgcn_s_setprio(0);
    SBAR();

#pragma unroll
    for (int fn = 0; fn < 2; ++fn) {
      b1[fn][0] = *(const bf16x8*)&smem[base + bbase + 2048 + fn * 1024 + g0];
      b1[fn][1] = *(const bf16x8*)&smem[base + bbase + 2048 + fn * 1024 + g1];
    }
    SBAR();
    LGKM0();
    __builtin_amdgcn_s_setprio(1);
#pragma unroll
    for (int kh = 0; kh < 2; ++kh)
#pragma unroll
      for (int fm = 0; fm < 4; ++fm)
#pragma unroll
        for (int fn = 0; fn < 2; ++fn)
          acc[fm][2 + fn] = MFMA16(b1[fn][kh], a[fm][kh], acc[fm][2 + fn]);
    __builtin_amdgcn_s_setprio(0);
    SBAR();

#pragma unroll
    for (int fm = 0; fm < 4; ++fm) {
      a[fm][0] = *(const bf16x8*)&smem[base + abase + 4096 + fm * 1024 + g0];
      a[fm][1] = *(const bf16x8*)&smem[base + abase + 4096 + fm * 1024 + g1];
    }
    SBAR();
    LGKM0();
    __builtin_amdgcn_s_setprio(1);
#pragma unroll
    for (int kh = 0; kh < 2; ++kh)
#pragma unroll
      for (int fm = 0; fm < 4; ++fm)
#pragma unroll
        for (int fn = 0; fn < 2; ++fn)
          acc[4 + fm][2 + fn] = MFMA16(b1[fn][kh], a[fm][kh], acc[4 + fm][2 + fn]);
    __builtin_amdgcn_s_setprio(0);
    SBAR();

    if (T + 2 < nt) {
      STAGE(T + 2, 0, 0);
      VMCNT(2);
    } else if (T + 1 < nt) {
      VMCNT(0);
    }
    SBAR();
    __builtin_amdgcn_s_setprio(1);
#pragma unroll
    for (int kh = 0; kh < 2; ++kh)
#pragma unroll
      for (int fm = 0; fm < 4; ++fm)
#pragma unroll
        for (int fn = 0; fn < 2; ++fn)
          acc[4 + fm][fn] = MFMA16(b0[fn][kh], a[fm][kh], acc[4 + fm][fn]);
    __builtin_amdgcn_s_setprio(0);
    SBAR();
  }
#undef STAGE

  // fp32 epilogue in two n-halves via LDS transpose
  __syncthreads();
  char* ef = (char*)smem;
#pragma unroll
  for (int half = 0; half < 2; ++half) {
    if ((wn >> 1) == half) {
#pragma unroll
      for (int fn = 0; fn < 4; ++fn) {
        const int nl = (wn & 1) * 64 + fn * 16 + q4 * 4;  // 0..127
        const f32x4 bn = *(const f32x4*)&bias[n0 + half * 128 + nl];
        const int slot = nl >> 2;
#pragma unroll
        for (int fm = 0; fm < 8; ++fm) {
          const int tok = wm * 128 + fm * 16 + m16;
          f32x4 v;
#pragma unroll
          for (int r = 0; r < 4; ++r) v[r] = acc[fm][fn][r] + bn[r];
          *(f32x4*)(ef + tok * 512 + ((slot ^ (tok & 7)) << 4)) = v;
        }
      }
    }
    __syncthreads();
#pragma unroll
    for (int pass = 0; pass < 16; ++pass) {
      const int tokr = pass * 16 + (tid >> 5);
      const int slot = tid & 31;
      const f32x4 vv = *(const f32x4*)(ef + tokr * 512 + ((slot ^ (tokr & 7)) << 4));
      *(f32x4*)(out + (size_t)(m0 + tokr) * N + n0 + half * 128 + slot * 4) = vv;
    }
    __syncthreads();
  }
}

// ---------------------------------------------------------------- attention (r2 structure)
// grid (128, 12, 2): b, h, half — the two halves sharing (b,h) K/V differ by
// 1536 linear ids (=0 mod 8) -> same XCD, second half L2-hits K/V.
// block 512 = 8 waves; wave w owns 16 Q-rows. K and V^T staged in LDS
// (XOR-group swizzle). P round-trip reuses the K LDS region after a barrier.
// (Measured: this structure = 101 us. P-XOR-swizzle variants, barrier removal,
// setprio, V-global-direct all regressed — r3/r4/r5.) Only delta vs r2:
// raw v_exp_f32 via __builtin_amdgcn_exp2f (drops libm's denorm-fixup VALU).
__global__ __launch_bounds__(512, 4) void attn_kernel(const __bf16* __restrict__ qb,
                                                      const __bf16* __restrict__ kb,
                                                      const __bf16* __restrict__ vtb,
                                                      const float* __restrict__ biasT,
                                                      __bf16* __restrict__ o_ws) {
  __shared__ __bf16 klds[256 * 64];  // 32 KB, reused for P after S-phase
  __shared__ __bf16 vlds[64 * 256];  // 32 KB
  const int tid = threadIdx.x;
  const int lane = tid & 63, w = tid >> 6;  // w in [0,8)
  const int m16 = lane & 15, q4 = lane >> 4;
  const int b = blockIdx.x, h = blockIdx.y;
  const size_t bh = (size_t)b * 12 + h;
  const __bf16* Q = qb + bh * (256 * 64);
  const __bf16* Kp = kb + bh * (256 * 64);
  const __bf16* Vt = vtb + bh * (64 * 256);
  const float* BhT = biasT + (size_t)h * 65536;
  const int qbase = blockIdx.z * 128;
  const int qrow0 = qbase + w * 16;  // this wave's 16 Q-rows

  // --- stage K: wave w covers rows [w*32, w*32+32), 4 insts x 8 rows x 128 B
#pragma unroll
  for (int i = 0; i < 4; ++i) {
    const int row = w * 32 + i * 8 + (lane >> 3);
    const int col = ((lane & 7) ^ (row & 7)) * 8;
    gload_lds16(Kp + (size_t)row * 64 + col, &klds[(w * 32 + i * 8) * 64]);
  }
  // --- stage V^T: wave w covers rows [w*8, w*8+8), 4 insts x 2 rows x 512 B
#pragma unroll
  for (int i = 0; i < 4; ++i) {
    const int row = w * 8 + i * 2 + (lane >> 5);
    const int g = lane & 31;
    const int gp = (g & 24) | ((g & 7) ^ (row & 7));
    gload_lds16(Vt + (size_t)row * 256 + gp * 8, &vlds[(w * 8 + i * 2) * 256]);
  }

  // --- Q frags (A-layout) from global, overlaps staging
  bf16x8 qf[2];
#pragma unroll
  for (int t = 0; t < 2; ++t)
    qf[t] = *(const bf16x8*)(Q + (size_t)(qrow0 + m16) * 64 + t * 32 + q4 * 8);

  __syncthreads();  // staging complete (barrier drains vmcnt)

  // --- S = (Q*scale) K^T from LDS
  f32x4 s[16];
#pragma unroll
  for (int c = 0; c < 16; ++c) {
    const int krow = c * 16 + m16;
    const bf16x8 kf0 = *(const bf16x8*)&klds[krow * 64 + ((q4 ^ (m16 & 7)) * 8)];
    const bf16x8 kf1 = *(const bf16x8*)&klds[krow * 64 + (((4 + q4) ^ (m16 & 7)) * 8)];
    f32x4 z = {0.f, 0.f, 0.f, 0.f};
    z = MFMA16(qf[0], kf0, z);
    s[c] = MFMA16(qf[1], kf1, z);
  }

  // --- + rel-pos bias, f32x4 along the q-row dim (transposed gather layout)
#pragma unroll
  for (int c = 0; c < 16; ++c) {
    const f32x4 bv = *(const f32x4*)&BhT[(size_t)(c * 16 + m16) * 256 + qrow0 + q4 * 4];
    s[c] += bv;
  }

  // --- full-row softmax; row owned by the 16 lanes sharing q4
  float linv[4];
#pragma unroll
  for (int r = 0; r < 4; ++r) {
    float mx = s[0][r];
#pragma unroll
    for (int c = 1; c < 16; ++c) mx = fmaxf(mx, s[c][r]);
    mx = fmaxf(mx, __shfl_xor(mx, 1));
    mx = fmaxf(mx, __shfl_xor(mx, 2));
    mx = fmaxf(mx, __shfl_xor(mx, 4));
    mx = fmaxf(mx, __shfl_xor(mx, 8));
    float sum = 0.f;
#pragma unroll
    for (int c = 0; c < 16; ++c) {
      const float p = __builtin_amdgcn_exp2f((s[c][r] - mx) * 1.4426950408889634f);
      s[c][r] = p;
      sum += p;
    }
    sum += __shfl_xor(sum, 1);
    sum += __shfl_xor(sum, 2);
    sum += __shfl_xor(sum, 4);
    sum += __shfl_xor(sum, 8);
    linv[r] = 1.f / sum;
  }

  __syncthreads();  // all K ds_reads done before P overwrites the K region

  // --- O = P V; P round-trips through per-wave slice of the K region
  f32x4 o[4] = {};
  __bf16* P = &klds[w * 1152];  // 16 rows x 72 elems (16-B aligned rows)
#pragma unroll
  for (int ch = 0; ch < 4; ++ch) {
#pragma unroll
    for (int cc = 0; cc < 4; ++cc)
#pragma unroll
      for (int r = 0; r < 4; ++r)
        P[(q4 * 4 + r) * 72 + cc * 16 + m16] = (__bf16)s[ch * 4 + cc][r];
    // same-wave LDS RAW/WAR: compiler lgkmcnt waits, no barrier needed
#pragma unroll
    for (int kt = 0; kt < 2; ++kt) {
      const bf16x8 pf = *(const bf16x8*)(P + m16 * 72 + kt * 32 + q4 * 8);
#pragma unroll
      for (int dt = 0; dt < 4; ++dt) {
        const int vrow = dt * 16 + m16;
        const bf16x8 vf = *(const bf16x8*)&vlds[vrow * 256 + ch * 64 +
                                                (((kt * 4 + q4) ^ (m16 & 7)) * 8)];
        o[dt] = MFMA16(pf, vf, o[dt]);
      }
    }
  }

  // --- normalize + store bf16 [b*n][h*64+d] for the out-proj GEMM
#pragma unroll
  for (int dt = 0; dt < 4; ++dt)
#pragma unroll
    for (int r = 0; r < 4; ++r) {
      const float v = o[dt][r] * linv[r];
      const size_t row = (size_t)b * 256 + qrow0 + q4 * 4 + r;
      o_ws[row * 768 + h * 64 + dt * 16 + m16] = (__bf16)v;
    }
}

// ---------------------------------------------------------------- launch
extern "C" void kernel_launch(void* const* d_in, const int* in_sizes, int n_in,
                              void* d_out, int out_size, void* d_ws, size_t ws_size,
                              hipStream_t stream) {
  const float* x = (const float*)d_in[0];      // [128,256,768]
  const float* Wqkv = (const float*)d_in[1];   // [768,2304]
  const float* bqkv = (const float*)d_in[2];   // [2304]
  const float* Wout = (const float*)d_in[3];   // [768,768]
  const float* bout = (const float*)d_in[4];   // [768]
  const float* table = (const float*)d_in[5];  // [961,12]
  const int* ids = (const int*)d_in[6];        // [65536]
  float* out = (float*)d_out;

  char* ws = (char*)d_ws;
  __bf16* xbf = (__bf16*)ws;                             // 50331648 B (alias: o_ws)
  __bf16* wqkvt = (__bf16*)(ws + 50331648);              //  3538944 B
  __bf16* woutt = (__bf16*)(ws + 53870592);              //  1179648 B
  __bf16* qbuf = (__bf16*)(ws + 55050240);               // 50331648 B
  __bf16* kbuf = (__bf16*)(ws + 105381888);              // 50331648 B
  __bf16* vtbuf = (__bf16*)(ws + 155713536);             // 50331648 B
  float* biasT = (float*)(ws + 206045184);               //  3145728 B

  // fused prep: conv + both weight transposes + bias gather, one dispatch
  prep_kernel<<<29952, 256, 0, stream>>>(x, xbf, Wqkv, wqkvt, Wout, woutt,
                                         table, ids, biasT);
  // Fused QKV projection: N = 2304 in one launch, 9 N-tiles x 128 M-tiles
  gemm8_qkv_kernel<9><<<1152, 512, 0, stream>>>(xbf, wqkvt, bqkv, qbuf, kbuf, vtbuf,
                                                32768, 768);
  attn_kernel<<<dim3(128, 12, 2), 512, 0, stream>>>(qbuf, kbuf, vtbuf, biasT, xbf /*o_ws*/);
  gemm8_out_kernel<3><<<384, 512, 0, stream>>>(xbf, woutt, bout, out, 32768, 768, 768);
}